// Round 13
// baseline (1994.994 us; speedup 1.0000x reference)
//
#include <hip/hip_runtime.h>
#include <hip/hip_bf16.h>
#include <stdint.h>

#define NTOK 8192
#define HD   2048
#define ID   5632
#define NE   8
#define NASSIGN (NTOK * 2)
#define MAXT256 (NASSIGN / 256 + NE)   // 72

typedef __attribute__((ext_vector_type(8)))  short bf16x8;
typedef __attribute__((ext_vector_type(4)))  float f32x4;
typedef __attribute__((ext_vector_type(16))) float f32x16;
typedef __attribute__((ext_vector_type(8)))  unsigned short u16x8;

__device__ __forceinline__ unsigned short f2bf(float f) {
  union { float f; unsigned int u; } c; c.f = f;
  unsigned int lsb = (c.u >> 16) & 1u;
  return (unsigned short)((c.u + 0x7fffu + lsb) >> 16);
}

__device__ __forceinline__ void async16(const void* g, void* l) {
  __builtin_amdgcn_global_load_lds(
      (const __attribute__((address_space(1))) void*)g,
      (__attribute__((address_space(3))) void*)l, 16, 0, 0);
}

// ---------------- router ----------------
__global__ __launch_bounds__(256) void k_router(
    const float* __restrict__ x, const float* __restrict__ rw,
    float* __restrict__ out_logits, float* __restrict__ out_topi,
    float* __restrict__ out_topw,
    int* __restrict__ tk_e, float* __restrict__ tk_w, int* __restrict__ cnts)
{
  const int wid = threadIdx.x >> 6, lane = threadIdx.x & 63;
  const int t = blockIdx.x * 4 + wid;
  const float* xr = x + (size_t)t * HD;
  float acc[NE];
#pragma unroll
  for (int e = 0; e < NE; e++) acc[e] = 0.f;
#pragma unroll
  for (int i = 0; i < 8; i++) {
    const int col = lane * 4 + i * 256;
    const float4 xv = *(const float4*)(xr + col);
#pragma unroll
    for (int e = 0; e < NE; e++) {
      const float4 wv = *(const float4*)(rw + e * HD + col);
      acc[e] += xv.x * wv.x + xv.y * wv.y + xv.z * wv.z + xv.w * wv.w;
    }
  }
#pragma unroll
  for (int e = 0; e < NE; e++)
    for (int o = 32; o >= 1; o >>= 1) acc[e] += __shfl_xor(acc[e], o, 64);

  if (lane == 0) {
    int i1 = 0;
#pragma unroll
    for (int e = 1; e < NE; e++) if (acc[e] > acc[i1]) i1 = e;
    int i2 = (i1 == 0) ? 1 : 0;
#pragma unroll
    for (int e = 0; e < NE; e++) if (e != i1 && acc[e] > acc[i2]) i2 = e;
    float p2 = __expf(acc[i2] - acc[i1]);
    float s  = 1.f + p2;
    float w1 = 1.f / s, w2 = p2 / s;
#pragma unroll
    for (int e = 0; e < NE; e++) out_logits[(size_t)t * NE + e] = acc[e];
    out_topi[t * 2 + 0] = (float)i1; out_topi[t * 2 + 1] = (float)i2;
    out_topw[t * 2 + 0] = w1;        out_topw[t * 2 + 1] = w2;
    tk_e[t * 2 + 0] = i1; tk_e[t * 2 + 1] = i2;
    tk_w[t * 2 + 0] = w1; tk_w[t * 2 + 1] = w2;
    atomicAdd(&cnts[i1], 1); atomicAdd(&cnts[i2], 1);
  }
}

__global__ void k_scan(const int* __restrict__ cnts, int* __restrict__ offs,
                       int* __restrict__ cursor, int* __restrict__ tile_e,
                       int* __restrict__ tile_rt, int* __restrict__ ntiles) {
  if (threadIdx.x == 0) {
    int s = 0, nt = 0;
    for (int e = 0; e < NE; e++) {
      offs[e] = s; cursor[e] = s;
      int ntl = (cnts[e] + 255) >> 8;
      for (int i = 0; i < ntl; i++) { tile_e[nt] = e; tile_rt[nt] = i; nt++; }
      s += cnts[e];
    }
    ntiles[0] = nt;
  }
}

__global__ void k_assign(const int* __restrict__ tk_e, const float* __restrict__ tk_w,
                         int* __restrict__ cursor, int* __restrict__ perm,
                         float* __restrict__ pw, int* __restrict__ inv) {
  int t = blockIdx.x * 256 + threadIdx.x;
  if (t >= NTOK) return;
#pragma unroll
  for (int k = 0; k < 2; k++) {
    int e = tk_e[t * 2 + k];
    int pos = atomicAdd(&cursor[e], 1);
    perm[pos] = t;
    pw[pos] = tk_w[t * 2 + k];
    inv[t * 2 + k] = pos;
  }
}

__global__ __launch_bounds__(256) void k_gather(const float* __restrict__ x,
    const int* __restrict__ perm, unsigned short* __restrict__ xg) {
  const int r = blockIdx.x;
  const int tok = perm[r];
  const float* src = x + (size_t)tok * HD;
  unsigned short* dst = xg + (size_t)r * HD;
  const int c = threadIdx.x * 8;
  float4 a = *(const float4*)(src + c);
  float4 b = *(const float4*)(src + c + 4);
  u16x8 o;
  o[0] = f2bf(a.x); o[1] = f2bf(a.y); o[2] = f2bf(a.z); o[3] = f2bf(a.w);
  o[4] = f2bf(b.x); o[5] = f2bf(b.y); o[6] = f2bf(b.z); o[7] = f2bf(b.w);
  *(u16x8*)(dst + c) = o;
}

// ---- transpose+convert: in fp32 [R][C] -> out bf16 [C][R], 64x64 tiles ----
__global__ __launch_bounds__(256) void k_conv64(const float* __restrict__ in0,
    const float* __restrict__ in1, unsigned short* __restrict__ out0,
    unsigned short* __restrict__ out1, int R, int C, int nmat) {
  __shared__ unsigned short tlb[64][72];   // row stride 144B
  const int z = blockIdx.z;
  const int mat = (nmat == 2) ? (z & 1) : 0;
  const int e   = (nmat == 2) ? (z >> 1) : z;
  const float* in = ((mat == 0) ? in0 : in1) + (size_t)e * R * C;
  unsigned short* out = ((mat == 0) ? out0 : out1) + (size_t)e * (size_t)R * C;
  const int tid = threadIdx.x;
  const int c0 = blockIdx.x * 64, r0 = blockIdx.y * 64;
#pragma unroll
  for (int pass = 0; pass < 4; ++pass) {
    const int kr = pass * 16 + (tid >> 4);
    const int cc = (tid & 15) * 4;
    const float4 v = *(const float4*)(in + (size_t)(r0 + kr) * C + c0 + cc);
    tlb[cc + 0][kr] = f2bf(v.x); tlb[cc + 1][kr] = f2bf(v.y);
    tlb[cc + 2][kr] = f2bf(v.z); tlb[cc + 3][kr] = f2bf(v.w);
  }
  __syncthreads();
#pragma unroll
  for (int pass = 0; pass < 2; ++pass) {
    const int n = pass * 32 + (tid >> 3);
    const int k = (tid & 7) * 8;
    *(u16x8*)(out + (size_t)(c0 + n) * R + r0 + k) = *(const u16x8*)&tlb[n][k];
  }
}

// ========= fused gate+up 256x(128+128) 8-phase GEMM, 32x32x16 MFMA =========
// R13: MFMA shape 16x16x32 -> 32x32x16 (same operand bytes, 2x FLOP/instr,
// 4096 vs 3378 FLOP/cyc): phase MFMA term 621->516 cyc. Fragment reads use
// the SAME R7 swizzle (derived conflict-free for the 32-row pattern:
// granule (4(row&1)+slot')&7 spreads 64 lanes 8/granule). C/D map (m74/m101):
// col=lane&31, row=(reg&3)+8*(reg>>2)+4*(lane>>5).
#define HBF(b,kh) (((b)*2+(kh))*32768)

__global__ __launch_bounds__(512, 2) void k_gemm_gu256f(
    const unsigned short* __restrict__ A,
    const unsigned short* __restrict__ BgT, const unsigned short* __restrict__ BuT,
    const int* __restrict__ cnts, const int* __restrict__ offs,
    const int* __restrict__ tile_e, const int* __restrict__ tile_rt,
    const int* __restrict__ ntiles, unsigned short* __restrict__ gact)
{
  const int raw = blockIdx.x;
  const int v = (raw & 7) * ((int)gridDim.x >> 3) + (raw >> 3);
  const int ct = v / MAXT256;            // [0,44)
  const int ti = v % MAXT256;
  if (ti >= ntiles[0]) return;
  const int e = tile_e[ti], rt = tile_rt[ti];
  const int cnt = cnts[e], off = offs[e];
  const int tid = threadIdx.x;

  __shared__ __align__(16) char smem[131072];

  const unsigned short* Bg = BgT + (size_t)e * (size_t)ID * HD;
  const unsigned short* Bu = BuT + (size_t)e * (size_t)ID * HD;
  const size_t arow0 = (size_t)off + (size_t)rt * 256;
  const size_t bcol0 = (size_t)ct * 128;

  const int r0s = tid >> 2;
  const int c0s = (((tid & 3) ^ ((tid >> 3) & 3)) * 8);

  const int NT = HD / 64, NIT = NT / 2;   // 32, 16

  auto STAGE_A = [&](int bb, int kh, int kt) {
    const int kc = kt * 64 + kh * 32;
    async16(A + (arow0 + r0s) * (size_t)HD + kc + c0s, smem + HBF(bb,kh) + tid * 16);
    async16(A + (arow0 + 128 + r0s) * (size_t)HD + kc + c0s, smem + HBF(bb,kh) + 8192 + tid * 16);
  };
  auto STAGE_B = [&](int bb, int kh, int kt) {
    const int kc = kt * 64 + kh * 32;
    async16(Bg + (bcol0 + r0s) * (size_t)HD + kc + c0s, smem + HBF(bb,kh) + 16384 + tid * 16);
    async16(Bu + (bcol0 + r0s) * (size_t)HD + kc + c0s, smem + HBF(bb,kh) + 24576 + tid * 16);
  };

  f32x16 accg[4], accu[4];
#pragma unroll
  for (int m = 0; m < 4; m++) { accg[m] = (f32x16)0.f; accu[m] = (f32x16)0.f; }

  const int lane = tid & 63, wid = tid >> 6;
  const int wm = wid >> 2, wn = wid & 3;          // 2M x 4N
  const int lrow = lane & 31, lx = lane >> 5;
  const int lswz = (lrow >> 1) & 3;

  STAGE_A(0,0,0); STAGE_B(0,0,0); STAGE_A(0,1,0); STAGE_B(0,1,0);
  STAGE_A(1,0,1); STAGE_B(1,0,1);
  asm volatile("s_waitcnt vmcnt(4)" ::: "memory");
  asm volatile("s_barrier" ::: "memory");

  constexpr int SB[8]  = {1,1,0,0,0,0,1,1};
  constexpr int SOP[8] = {0,1,0,1,0,1,0,1};
  constexpr int SKH[8] = {1,1,0,0,1,1,0,0};
  constexpr int SKO[8] = {1,1,2,2,2,2,3,3};

  bf16x8 bgr[2], bur[2];
  for (int i = 0; i < NIT; ++i) {
#pragma unroll
    for (int p = 0; p < 8; ++p) {
      const int b = p >> 2, kh = (p >> 1) & 1, mh = p & 1;
      bf16x8 afr[2][2];
#pragma unroll
      for (int mt2 = 0; mt2 < 2; mt2++)
#pragma unroll
        for (int ks = 0; ks < 2; ks++)
          afr[mt2][ks] = *(const bf16x8*)(smem + HBF(b,kh)
              + ((wm*128 + mh*64 + mt2*32 + lrow) << 6)
              + ((((ks << 1) + lx) ^ lswz) << 4));
      if (mh == 0) {
#pragma unroll
        for (int ks = 0; ks < 2; ks++) {
          bgr[ks] = *(const bf16x8*)(smem + HBF(b,kh) + 16384
              + ((wn*32 + lrow) << 6) + ((((ks << 1) + lx) ^ lswz) << 4));
          bur[ks] = *(const bf16x8*)(smem + HBF(b,kh) + 24576
              + ((wn*32 + lrow) << 6) + ((((ks << 1) + lx) ^ lswz) << 4));
        }
      }
      {
        int kt = 2 * i + SKO[p]; kt = kt < NT - 1 ? kt : NT - 1;
        if (SOP[p] == 0) STAGE_A(SB[p], SKH[p], kt);
        else             STAGE_B(SB[p], SKH[p], kt);
      }
      asm volatile("s_barrier" ::: "memory");
      __builtin_amdgcn_s_setprio(1);
#pragma unroll
      for (int mt2 = 0; mt2 < 2; mt2++)
#pragma unroll
        for (int ks = 0; ks < 2; ks++) {
          accg[mh*2 + mt2] = __builtin_amdgcn_mfma_f32_32x32x16_bf16(
              afr[mt2][ks], bgr[ks], accg[mh*2 + mt2], 0, 0, 0);
          accu[mh*2 + mt2] = __builtin_amdgcn_mfma_f32_32x32x16_bf16(
              afr[mt2][ks], bur[ks], accu[mh*2 + mt2], 0, 0, 0);
        }
      __builtin_amdgcn_s_setprio(0);
      if (p == 3 || p == 7) asm volatile("s_waitcnt vmcnt(4)" ::: "memory");
      asm volatile("s_barrier" ::: "memory");
    }
  }
  asm volatile("s_waitcnt vmcnt(0)" ::: "memory");

  // epilogue: silu(g)*u; C/D: col=lane&31, row=(j&3)+8*(j>>2)+4*(lane>>5)
  const int ccol = lane & 31, rsub = (lane >> 5) * 4;
  const int rbase = rt * 256 + wm * 128;
  const int col = (int)bcol0 + wn * 32 + ccol;
#pragma unroll
  for (int mt = 0; mt < 4; ++mt) {
#pragma unroll
    for (int j = 0; j < 16; ++j) {
      const int rl = rbase + mt * 32 + (j & 3) + ((j >> 2) << 3) + rsub;
      if (rl >= cnt) continue;
      const size_t grow = (size_t)off + rl;
      const float g = accg[mt][j], u = accu[mt][j];
      const float a = g / (1.f + __expf(-g)) * u;
      gact[grow * (size_t)ID + col] = f2bf(a);
    }
  }
}

// ===== down 256x256 8-phase GEMM, 32x32x16 MFMA, K-split x2 -> dbuf =====
#define HB(b,kh,op) (((((b)*2+(kh))*2)+(op))*16384)

__global__ __launch_bounds__(512, 2) void k_gemm_dn256(
    const unsigned short* __restrict__ A,     // gact [rows][ID]
    const unsigned short* __restrict__ Wbase, // [NE][HD][ID]
    const int* __restrict__ cnts, const int* __restrict__ offs,
    const int* __restrict__ tile_e, const int* __restrict__ tile_rt,
    const int* __restrict__ ntiles,
    const float* __restrict__ pw, float* __restrict__ dbuf)
{
  const int raw = blockIdx.x;
  const int v = (raw & 7) * ((int)gridDim.x >> 3) + (raw >> 3);
  const int ti = v % MAXT256;
  const int rest = v / MAXT256;
  const int ksplit = rest & 1;           // K-half
  const int ct = rest >> 1;              // [0,8)
  if (ti >= ntiles[0]) return;
  const int e = tile_e[ti], rt = tile_rt[ti];
  const int cnt = cnts[e], off = offs[e];
  const int tid = threadIdx.x;

  __shared__ __align__(16) char smem[131072];

  const unsigned short* W = Wbase + (size_t)e * (size_t)HD * ID;
  const size_t arow0 = (size_t)off + (size_t)rt * 256;
  const size_t bcol0 = (size_t)ct * 256;
  const int kbase = ksplit * (ID / 2);

  const int r0s = tid >> 2;
  const int c0s = (((tid & 3) ^ ((tid >> 3) & 3)) * 8);

  const int NT = (ID / 2) / 64, NIT = NT / 2;   // 44, 22

  auto STAGE_A = [&](int bb, int kh, int kt) {
    const int kc = kbase + kt * 64 + kh * 32;
    async16(A + (arow0 + r0s) * (size_t)ID + kc + c0s, smem + HB(bb,kh,0) + tid * 16);
    async16(A + (arow0 + 128 + r0s) * (size_t)ID + kc + c0s, smem + HB(bb,kh,0) + 8192 + tid * 16);
  };
  auto STAGE_B = [&](int bb, int kh, int kt) {
    const int kc = kbase + kt * 64 + kh * 32;
    async16(W + (bcol0 + r0s) * (size_t)ID + kc + c0s, smem + HB(bb,kh,1) + tid * 16);
    async16(W + (bcol0 + 128 + r0s) * (size_t)ID + kc + c0s, smem + HB(bb,kh,1) + 8192 + tid * 16);
  };

  f32x16 acc[4][2];
#pragma unroll
  for (int m = 0; m < 4; m++)
#pragma unroll
    for (int n = 0; n < 2; n++) acc[m][n] = (f32x16)0.f;

  const int lane = tid & 63, wid = tid >> 6;
  const int wm = wid >> 2, wn = wid & 3;
  const int lrow = lane & 31, lx = lane >> 5;
  const int lswz = (lrow >> 1) & 3;

  STAGE_A(0,0,0); STAGE_B(0,0,0); STAGE_A(0,1,0); STAGE_B(0,1,0);
  STAGE_A(1,0,1); STAGE_B(1,0,1);
  asm volatile("s_waitcnt vmcnt(4)" ::: "memory");
  asm volatile("s_barrier" ::: "memory");

  constexpr int SB[8]  = {1,1,0,0,0,0,1,1};
  constexpr int SOP[8] = {0,1,0,1,0,1,0,1};
  constexpr int SKH[8] = {1,1,0,0,1,1,0,0};
  constexpr int SKO[8] = {1,1,2,2,2,2,3,3};

  bf16x8 bfr[2][2];
  for (int i = 0; i < NIT; ++i) {
#pragma unroll
    for (int p = 0; p < 8; ++p) {
      const int b = p >> 2, kh = (p >> 1) & 1, mh = p & 1;
      bf16x8 afr[2][2];
#pragma unroll
      for (int mt2 = 0; mt2 < 2; mt2++)
#pragma unroll
        for (int ks = 0; ks < 2; ks++)
          afr[mt2][ks] = *(const bf16x8*)(smem + HB(b,kh,0)
              + ((wm*128 + mh*64 + mt2*32 + lrow) << 6)
              + ((((ks << 1) + lx) ^ lswz) << 4));
      if (mh == 0) {
#pragma unroll
        for (int nt = 0; nt < 2; nt++)
#pragma unroll
          for (int ks = 0; ks < 2; ks++)
            bfr[nt][ks] = *(const bf16x8*)(smem + HB(b,kh,1)
                + ((wn*64 + nt*32 + lrow) << 6)
                + ((((ks << 1) + lx) ^ lswz) << 4));
      }
      {
        int kt = 2 * i + SKO[p]; kt = kt < NT - 1 ? kt : NT - 1;
        if (SOP[p] == 0) STAGE_A(SB[p], SKH[p], kt);
        else             STAGE_B(SB[p], SKH[p], kt);
      }
      asm volatile("s_barrier" ::: "memory");
      __builtin_amdgcn_s_setprio(1);
#pragma unroll
      for (int mt2 = 0; mt2 < 2; mt2++)
#pragma unroll
        for (int nt = 0; nt < 2; nt++)
#pragma unroll
          for (int ks = 0; ks < 2; ks++)
            acc[mh*2 + mt2][nt] = __builtin_amdgcn_mfma_f32_32x32x16_bf16(
                afr[mt2][ks], bfr[nt][ks], acc[mh*2 + mt2][nt], 0, 0, 0);
      __builtin_amdgcn_s_setprio(0);
      if (p == 3 || p == 7) asm volatile("s_waitcnt vmcnt(4)" ::: "memory");
      asm volatile("s_barrier" ::: "memory");
    }
  }
  asm volatile("s_waitcnt vmcnt(0)" ::: "memory");

  float* db = dbuf + (size_t)ksplit * (size_t)NASSIGN * HD;
  const int ccol = lane & 31, rsub = (lane >> 5) * 4;
  const int rbase = rt * 256 + wm * 128;
#pragma unroll
  for (int mt = 0; mt < 4; ++mt) {
#pragma unroll
    for (int j = 0; j < 16; ++j) {
      const int rl = rbase + mt * 32 + (j & 3) + ((j >> 2) << 3) + rsub;
      if (rl >= cnt) continue;
      const size_t grow = (size_t)off + rl;
      const float wgt = pw[grow];
#pragma unroll
      for (int nt = 0; nt < 2; ++nt) {
        const int col = (int)bcol0 + wn * 64 + nt * 32 + ccol;
        db[grow * (size_t)HD + col] = acc[mt][nt][j] * wgt;
      }
    }
  }
}

// ---- combine: out[t] = sum over {ksplit} x {2 assignments} of dbuf rows ----
__global__ __launch_bounds__(256) void k_combine(const float* __restrict__ dbuf,
    const int* __restrict__ inv, float* __restrict__ out) {
  const int t = blockIdx.x;
  const int p0 = inv[t * 2], p1 = inv[t * 2 + 1];
  const float* d1 = dbuf + (size_t)NASSIGN * HD;
  const float4* a0 = (const float4*)(dbuf + (size_t)p0 * HD);
  const float4* a1 = (const float4*)(dbuf + (size_t)p1 * HD);
  const float4* b0 = (const float4*)(d1 + (size_t)p0 * HD);
  const float4* b1 = (const float4*)(d1 + (size_t)p1 * HD);
  float4* o = (float4*)(out + (size_t)t * HD);
#pragma unroll
  for (int i = 0; i < 2; i++) {
    int c = threadIdx.x + i * 256;
    float4 x0 = a0[c], x1 = a1[c], y0 = b0[c], y1 = b1[c];
    o[c] = make_float4(x0.x + x1.x + y0.x + y1.x, x0.y + x1.y + y0.y + y1.y,
                       x0.z + x1.z + y0.z + y1.z, x0.w + x1.w + y0.w + y1.w);
  }
}

extern "C" void kernel_launch(void* const* d_in, const int* in_sizes, int n_in,
                              void* d_out, int out_size, void* d_ws, size_t ws_size,
                              hipStream_t stream) {
  const float* x  = (const float*)d_in[0];
  const float* rw = (const float*)d_in[1];
  const float* wg = (const float*)d_in[2];
  const float* wu = (const float*)d_in[3];
  const float* wd = (const float*)d_in[4];

  float* outp       = (float*)d_out;
  float* out_logits = outp + (size_t)NTOK * HD;
  float* out_topi   = out_logits + (size_t)NTOK * NE;
  float* out_topw   = out_topi + (size_t)NTOK * 2;

  char* w = (char*)d_ws;
  int*   cnts    = (int*)(w + 0);
  int*   offs    = (int*)(w + 64);
  int*   cursor  = (int*)(w + 128);
  int*   ntiles  = (int*)(w + 192);
  int*   tile_e  = (int*)(w + 256);
  int*   tile_rt = (int*)(w + 1280);
  int*   tk_e    = (int*)(w + 4096);
  float* tk_w    = (float*)(w + 4096 + 65536);
  int*   perm    = (int*)(w + 4096 + 2 * 65536);
  float* pw      = (float*)(w + 4096 + 3 * 65536);
  int*   inv     = (int*)(w + 4096 + 4 * 65536);

  char* big = w + (1 << 20);
  unsigned short* xg = (unsigned short*)big;                    // (NASSIGN+256) x HD
  const size_t XG_E = (size_t)(NASSIGN + 256) * HD;
  unsigned short* wgT = xg + XG_E;                              // [NE][ID][HD]
  const size_t WT_E = (size_t)NE * ID * HD;
  unsigned short* wuT  = wgT + WT_E;
  unsigned short* wdT  = wuT + WT_E;                            // [NE][HD][ID]
  unsigned short* gact = wdT + WT_E;                            // (NASSIGN+256) x ID
  const size_t GA_E = (size_t)(NASSIGN + 256) * ID;
  float* dbuf = (float*)(gact + GA_E);                          // 2 x NASSIGN x HD f32

  hipMemsetAsync(d_ws, 0, 256, stream);   // counters

  k_conv64<<<dim3(ID / 64, HD / 64, 2 * NE), 256, 0, stream>>>(
      wg, wu, wgT, wuT, HD, ID, 2);
  k_conv64<<<dim3(HD / 64, ID / 64, NE), 256, 0, stream>>>(
      wd, nullptr, wdT, nullptr, ID, HD, 1);

  k_router<<<NTOK / 4, 256, 0, stream>>>(x, rw, out_logits, out_topi, out_topw,
                                         tk_e, tk_w, cnts);
  k_scan<<<1, 64, 0, stream>>>(cnts, offs, cursor, tile_e, tile_rt, ntiles);
  k_assign<<<NTOK / 256, 256, 0, stream>>>(tk_e, tk_w, cursor, perm, pw, inv);
  k_gather<<<NASSIGN, 256, 0, stream>>>(x, perm, xg);

  // fused gate+up -> gact   (44 ct x 72 ti = 3168 blocks, %8==0)
  k_gemm_gu256f<<<dim3((ID / 128) * MAXT256), 512, 0, stream>>>(
      xg, wgT, wuT, cnts, offs, tile_e, tile_rt, ntiles, gact);
  // down (*pw) -> dbuf, K-split x2   (8 ct x 2 ks x 72 ti = 1152 blocks)
  k_gemm_dn256<<<dim3((HD / 256) * 2 * MAXT256), 512, 0, stream>>>(
      gact, wdT, cnts, offs, tile_e, tile_rt, ntiles, pw, dbuf);
  // out[t] = dbuf0[inv0]+dbuf0[inv1]+dbuf1[inv0]+dbuf1[inv1]
  k_combine<<<NTOK, 256, 0, stream>>>(dbuf, inv, outp);
}

// Round 14
// 1848.748 us; speedup vs baseline: 1.0791x; 1.0791x over previous
//
#include <hip/hip_runtime.h>
#include <hip/hip_bf16.h>
#include <stdint.h>

#define NTOK 8192
#define HD   2048
#define ID   5632
#define NE   8
#define NASSIGN (NTOK * 2)
#define MAXT256 (NASSIGN / 256 + NE)   // 72

typedef __attribute__((ext_vector_type(8))) short  bf16x8;
typedef __attribute__((ext_vector_type(4))) float  f32x4;
typedef __attribute__((ext_vector_type(8))) unsigned short u16x8;

__device__ __forceinline__ unsigned short f2bf(float f) {
  union { float f; unsigned int u; } c; c.f = f;
  unsigned int lsb = (c.u >> 16) & 1u;
  return (unsigned short)((c.u + 0x7fffu + lsb) >> 16);
}

__device__ __forceinline__ void async16(const void* g, void* l) {
  __builtin_amdgcn_global_load_lds(
      (const __attribute__((address_space(1))) void*)g,
      (__attribute__((address_space(3))) void*)l, 16, 0, 0);
}

// ---------------- router ----------------
__global__ __launch_bounds__(256) void k_router(
    const float* __restrict__ x, const float* __restrict__ rw,
    float* __restrict__ out_logits, float* __restrict__ out_topi,
    float* __restrict__ out_topw,
    int* __restrict__ tk_e, float* __restrict__ tk_w, int* __restrict__ cnts)
{
  const int wid = threadIdx.x >> 6, lane = threadIdx.x & 63;
  const int t = blockIdx.x * 4 + wid;
  const float* xr = x + (size_t)t * HD;
  float acc[NE];
#pragma unroll
  for (int e = 0; e < NE; e++) acc[e] = 0.f;
#pragma unroll
  for (int i = 0; i < 8; i++) {
    const int col = lane * 4 + i * 256;
    const float4 xv = *(const float4*)(xr + col);
#pragma unroll
    for (int e = 0; e < NE; e++) {
      const float4 wv = *(const float4*)(rw + e * HD + col);
      acc[e] += xv.x * wv.x + xv.y * wv.y + xv.z * wv.z + xv.w * wv.w;
    }
  }
#pragma unroll
  for (int e = 0; e < NE; e++)
    for (int o = 32; o >= 1; o >>= 1) acc[e] += __shfl_xor(acc[e], o, 64);

  if (lane == 0) {
    int i1 = 0;
#pragma unroll
    for (int e = 1; e < NE; e++) if (acc[e] > acc[i1]) i1 = e;
    int i2 = (i1 == 0) ? 1 : 0;
#pragma unroll
    for (int e = 0; e < NE; e++) if (e != i1 && acc[e] > acc[i2]) i2 = e;
    float p2 = __expf(acc[i2] - acc[i1]);
    float s  = 1.f + p2;
    float w1 = 1.f / s, w2 = p2 / s;
#pragma unroll
    for (int e = 0; e < NE; e++) out_logits[(size_t)t * NE + e] = acc[e];
    out_topi[t * 2 + 0] = (float)i1; out_topi[t * 2 + 1] = (float)i2;
    out_topw[t * 2 + 0] = w1;        out_topw[t * 2 + 1] = w2;
    tk_e[t * 2 + 0] = i1; tk_e[t * 2 + 1] = i2;
    tk_w[t * 2 + 0] = w1; tk_w[t * 2 + 1] = w2;
    atomicAdd(&cnts[i1], 1); atomicAdd(&cnts[i2], 1);
  }
}

__global__ void k_scan(const int* __restrict__ cnts, int* __restrict__ offs,
                       int* __restrict__ cursor, int* __restrict__ tile_e,
                       int* __restrict__ tile_rt, int* __restrict__ ntiles) {
  if (threadIdx.x == 0) {
    int s = 0, nt = 0;
    for (int e = 0; e < NE; e++) {
      offs[e] = s; cursor[e] = s;
      int ntl = (cnts[e] + 255) >> 8;
      for (int i = 0; i < ntl; i++) { tile_e[nt] = e; tile_rt[nt] = i; nt++; }
      s += cnts[e];
    }
    ntiles[0] = nt;
  }
}

__global__ void k_assign(const int* __restrict__ tk_e, const float* __restrict__ tk_w,
                         int* __restrict__ cursor, int* __restrict__ perm,
                         float* __restrict__ pw, int* __restrict__ inv) {
  int t = blockIdx.x * 256 + threadIdx.x;
  if (t >= NTOK) return;
#pragma unroll
  for (int k = 0; k < 2; k++) {
    int e = tk_e[t * 2 + k];
    int pos = atomicAdd(&cursor[e], 1);
    perm[pos] = t;
    pw[pos] = tk_w[t * 2 + k];
    inv[t * 2 + k] = pos;
  }
}

__global__ __launch_bounds__(256) void k_gather(const float* __restrict__ x,
    const int* __restrict__ perm, unsigned short* __restrict__ xg) {
  const int r = blockIdx.x;
  const int tok = perm[r];
  const float* src = x + (size_t)tok * HD;
  unsigned short* dst = xg + (size_t)r * HD;
  const int c = threadIdx.x * 8;
  float4 a = *(const float4*)(src + c);
  float4 b = *(const float4*)(src + c + 4);
  u16x8 o;
  o[0] = f2bf(a.x); o[1] = f2bf(a.y); o[2] = f2bf(a.z); o[3] = f2bf(a.w);
  o[4] = f2bf(b.x); o[5] = f2bf(b.y); o[6] = f2bf(b.z); o[7] = f2bf(b.w);
  *(u16x8*)(dst + c) = o;
}

// ---- transpose+convert: in fp32 [R][C] -> out bf16 [C][R], 64x64 tiles ----
__global__ __launch_bounds__(256) void k_conv64(const float* __restrict__ in0,
    const float* __restrict__ in1, unsigned short* __restrict__ out0,
    unsigned short* __restrict__ out1, int R, int C, int nmat) {
  __shared__ unsigned short tlb[64][72];   // row stride 144B
  const int z = blockIdx.z;
  const int mat = (nmat == 2) ? (z & 1) : 0;
  const int e   = (nmat == 2) ? (z >> 1) : z;
  const float* in = ((mat == 0) ? in0 : in1) + (size_t)e * R * C;
  unsigned short* out = ((mat == 0) ? out0 : out1) + (size_t)e * (size_t)R * C;
  const int tid = threadIdx.x;
  const int c0 = blockIdx.x * 64, r0 = blockIdx.y * 64;
#pragma unroll
  for (int pass = 0; pass < 4; ++pass) {
    const int kr = pass * 16 + (tid >> 4);
    const int cc = (tid & 15) * 4;
    const float4 v = *(const float4*)(in + (size_t)(r0 + kr) * C + c0 + cc);
    tlb[cc + 0][kr] = f2bf(v.x); tlb[cc + 1][kr] = f2bf(v.y);
    tlb[cc + 2][kr] = f2bf(v.z); tlb[cc + 3][kr] = f2bf(v.w);
  }
  __syncthreads();
#pragma unroll
  for (int pass = 0; pass < 2; ++pass) {
    const int n = pass * 32 + (tid >> 3);
    const int k = (tid & 7) * 8;
    *(u16x8*)(out + (size_t)(c0 + n) * R + r0 + k) = *(const u16x8*)&tlb[n][k];
  }
}

// ========= fused gate+up 256x(128+128) 8-phase MFMA GEMM (R12, verbatim) =========
#define HBF(b,kh) (((b)*2+(kh))*32768)

__global__ __launch_bounds__(512, 2) void k_gemm_gu256f(
    const unsigned short* __restrict__ A,
    const unsigned short* __restrict__ BgT, const unsigned short* __restrict__ BuT,
    const int* __restrict__ cnts, const int* __restrict__ offs,
    const int* __restrict__ tile_e, const int* __restrict__ tile_rt,
    const int* __restrict__ ntiles, unsigned short* __restrict__ gact)
{
  const int raw = blockIdx.x;
  const int v = (raw & 7) * ((int)gridDim.x >> 3) + (raw >> 3);
  const int ct = v / MAXT256;            // [0,44)
  const int ti = v % MAXT256;
  if (ti >= ntiles[0]) return;
  const int e = tile_e[ti], rt = tile_rt[ti];
  const int cnt = cnts[e], off = offs[e];
  const int tid = threadIdx.x;

  __shared__ __align__(16) char smem[131072];

  const unsigned short* Bg = BgT + (size_t)e * (size_t)ID * HD;
  const unsigned short* Bu = BuT + (size_t)e * (size_t)ID * HD;
  const size_t arow0 = (size_t)off + (size_t)rt * 256;
  const size_t bcol0 = (size_t)ct * 128;

  const int r0s = tid >> 2;
  const int c0s = (((tid & 3) ^ ((tid >> 3) & 3)) * 8);

  const int NT = HD / 64, NIT = NT / 2;   // 32, 16

  auto STAGE_A = [&](int bb, int kh, int kt) {
    const int kc = kt * 64 + kh * 32;
    async16(A + (arow0 + r0s) * (size_t)HD + kc + c0s, smem + HBF(bb,kh) + tid * 16);
    async16(A + (arow0 + 128 + r0s) * (size_t)HD + kc + c0s, smem + HBF(bb,kh) + 8192 + tid * 16);
  };
  auto STAGE_B = [&](int bb, int kh, int kt) {
    const int kc = kt * 64 + kh * 32;
    async16(Bg + (bcol0 + r0s) * (size_t)HD + kc + c0s, smem + HBF(bb,kh) + 16384 + tid * 16);
    async16(Bu + (bcol0 + r0s) * (size_t)HD + kc + c0s, smem + HBF(bb,kh) + 24576 + tid * 16);
  };

  f32x4 accg[8][2], accu[8][2];
#pragma unroll
  for (int m = 0; m < 8; m++)
#pragma unroll
    for (int n = 0; n < 2; n++) { accg[m][n] = (f32x4)0.f; accu[m][n] = (f32x4)0.f; }

  const int lane = tid & 63, wid = tid >> 6;
  const int wm = wid >> 2, wn = wid & 3;          // 2M x 4N
  const int fr = lane & 15;
  const int slot = ((lane >> 4) ^ ((fr >> 1) & 3));
  const int laddr = (fr << 6) + (slot << 4);

  STAGE_A(0,0,0); STAGE_B(0,0,0); STAGE_A(0,1,0); STAGE_B(0,1,0);
  STAGE_A(1,0,1); STAGE_B(1,0,1);
  asm volatile("s_waitcnt vmcnt(4)" ::: "memory");
  asm volatile("s_barrier" ::: "memory");

  constexpr int SB[8]  = {1,1,0,0,0,0,1,1};
  constexpr int SOP[8] = {0,1,0,1,0,1,0,1};
  constexpr int SKH[8] = {1,1,0,0,1,1,0,0};
  constexpr int SKO[8] = {1,1,2,2,2,2,3,3};

  bf16x8 bgr[2], bur[2];
  for (int i = 0; i < NIT; ++i) {
#pragma unroll
    for (int p = 0; p < 8; ++p) {
      const int b = p >> 2, kh = (p >> 1) & 1, mh = p & 1;
      bf16x8 afr[4];
#pragma unroll
      for (int t = 0; t < 4; t++)
        afr[t] = *(const bf16x8*)(smem + HBF(b,kh) + ((wm*128 + mh*64 + t*16) << 6) + laddr);
      if (mh == 0) {
#pragma unroll
        for (int t = 0; t < 2; t++) {
          bgr[t] = *(const bf16x8*)(smem + HBF(b,kh) + 16384 + ((wn*32 + t*16) << 6) + laddr);
          bur[t] = *(const bf16x8*)(smem + HBF(b,kh) + 24576 + ((wn*32 + t*16) << 6) + laddr);
        }
      }
      {
        int kt = 2 * i + SKO[p]; kt = kt < NT - 1 ? kt : NT - 1;
        if (SOP[p] == 0) STAGE_A(SB[p], SKH[p], kt);
        else             STAGE_B(SB[p], SKH[p], kt);
      }
      asm volatile("s_barrier" ::: "memory");
      __builtin_amdgcn_s_setprio(1);
#pragma unroll
      for (int t = 0; t < 4; t++)
#pragma unroll
        for (int n = 0; n < 2; n++) {
          accg[mh*4 + t][n] = __builtin_amdgcn_mfma_f32_16x16x32_bf16(afr[t], bgr[n], accg[mh*4 + t][n], 0, 0, 0);
          accu[mh*4 + t][n] = __builtin_amdgcn_mfma_f32_16x16x32_bf16(afr[t], bur[n], accu[mh*4 + t][n], 0, 0, 0);
        }
      __builtin_amdgcn_s_setprio(0);
      if (p == 3 || p == 7) asm volatile("s_waitcnt vmcnt(4)" ::: "memory");
      asm volatile("s_barrier" ::: "memory");
    }
  }
  asm volatile("s_waitcnt vmcnt(0)" ::: "memory");

  const int crow = (lane >> 4) * 4, ccol = lane & 15;
  const int rbase = rt * 256 + wm * 128;
#pragma unroll
  for (int mt = 0; mt < 8; ++mt) {
#pragma unroll
    for (int j = 0; j < 4; ++j) {
      const int rl = rbase + mt * 16 + crow + j;
      if (rl >= cnt) continue;
      const size_t grow = (size_t)off + rl;
#pragma unroll
      for (int nt = 0; nt < 2; ++nt) {
        const int col = (int)bcol0 + wn * 32 + nt * 16 + ccol;
        const float g = accg[mt][nt][j], u = accu[mt][nt][j];
        const float a = g / (1.f + __expf(-g)) * u;
        gact[grow * (size_t)ID + col] = f2bf(a);
      }
    }
  }
}

// ===== down 256x256 8-phase GEMM (R12 16x16 core) + K-split x2 -> dbuf =====
#define HB(b,kh,op) (((((b)*2+(kh))*2)+(op))*16384)

__global__ __launch_bounds__(512, 2) void k_gemm_dn256(
    const unsigned short* __restrict__ A,     // gact [rows][ID]
    const unsigned short* __restrict__ Wbase, // [NE][HD][ID]
    const int* __restrict__ cnts, const int* __restrict__ offs,
    const int* __restrict__ tile_e, const int* __restrict__ tile_rt,
    const int* __restrict__ ntiles,
    const float* __restrict__ pw, float* __restrict__ dbuf)
{
  const int raw = blockIdx.x;
  const int v = (raw & 7) * ((int)gridDim.x >> 3) + (raw >> 3);
  const int ti = v % MAXT256;
  const int rest = v / MAXT256;          // [0,16)
  const int ksplit = rest & 1;           // K-half
  const int ct = rest >> 1;              // [0,8)
  if (ti >= ntiles[0]) return;
  const int e = tile_e[ti], rt = tile_rt[ti];
  const int cnt = cnts[e], off = offs[e];
  const int tid = threadIdx.x;

  __shared__ __align__(16) char smem[131072];

  const unsigned short* W = Wbase + (size_t)e * (size_t)HD * ID;
  const size_t arow0 = (size_t)off + (size_t)rt * 256;
  const size_t bcol0 = (size_t)ct * 256;
  const int kbase = ksplit * (ID / 2);

  const int r0s = tid >> 2;
  const int c0s = (((tid & 3) ^ ((tid >> 3) & 3)) * 8);

  const int NT = (ID / 2) / 64, NIT = NT / 2;   // 44, 22

  auto STAGE_A = [&](int bb, int kh, int kt) {
    const int kc = kbase + kt * 64 + kh * 32;
    async16(A + (arow0 + r0s) * (size_t)ID + kc + c0s, smem + HB(bb,kh,0) + tid * 16);
    async16(A + (arow0 + 128 + r0s) * (size_t)ID + kc + c0s, smem + HB(bb,kh,0) + 8192 + tid * 16);
  };
  auto STAGE_B = [&](int bb, int kh, int kt) {
    const int kc = kbase + kt * 64 + kh * 32;
    async16(W + (bcol0 + r0s) * (size_t)ID + kc + c0s, smem + HB(bb,kh,1) + tid * 16);
    async16(W + (bcol0 + 128 + r0s) * (size_t)ID + kc + c0s, smem + HB(bb,kh,1) + 8192 + tid * 16);
  };

  f32x4 acc[8][4];
#pragma unroll
  for (int m = 0; m < 8; m++)
#pragma unroll
    for (int n = 0; n < 4; n++) acc[m][n] = (f32x4)0.f;

  const int lane = tid & 63, wid = tid >> 6;
  const int wm = wid >> 2, wn = wid & 3;
  const int fr = lane & 15;
  const int slot = ((lane >> 4) ^ ((fr >> 1) & 3));
  const int laddr = (fr << 6) + (slot << 4);

  STAGE_A(0,0,0); STAGE_B(0,0,0); STAGE_A(0,1,0); STAGE_B(0,1,0);
  STAGE_A(1,0,1); STAGE_B(1,0,1);
  asm volatile("s_waitcnt vmcnt(4)" ::: "memory");
  asm volatile("s_barrier" ::: "memory");

  constexpr int SB[8]  = {1,1,0,0,0,0,1,1};
  constexpr int SOP[8] = {0,1,0,1,0,1,0,1};
  constexpr int SKH[8] = {1,1,0,0,1,1,0,0};
  constexpr int SKO[8] = {1,1,2,2,2,2,3,3};

  bf16x8 bfr[4];
  for (int i = 0; i < NIT; ++i) {
#pragma unroll
    for (int p = 0; p < 8; ++p) {
      const int b = p >> 2, kh = (p >> 1) & 1, mh = p & 1;
      bf16x8 afr[4];
#pragma unroll
      for (int t = 0; t < 4; t++)
        afr[t] = *(const bf16x8*)(smem + HB(b,kh,0) + ((wm*128 + mh*64 + t*16) << 6) + laddr);
      if (mh == 0) {
#pragma unroll
        for (int t = 0; t < 4; t++)
          bfr[t] = *(const bf16x8*)(smem + HB(b,kh,1) + ((wn*64 + t*16) << 6) + laddr);
      }
      {
        int kt = 2 * i + SKO[p]; kt = kt < NT - 1 ? kt : NT - 1;
        if (SOP[p] == 0) STAGE_A(SB[p], SKH[p], kt);
        else             STAGE_B(SB[p], SKH[p], kt);
      }
      asm volatile("s_barrier" ::: "memory");
      __builtin_amdgcn_s_setprio(1);
#pragma unroll
      for (int t = 0; t < 4; t++)
#pragma unroll
        for (int n = 0; n < 4; n++)
          acc[mh*4 + t][n] = __builtin_amdgcn_mfma_f32_16x16x32_bf16(afr[t], bfr[n], acc[mh*4 + t][n], 0, 0, 0);
      __builtin_amdgcn_s_setprio(0);
      if (p == 3 || p == 7) asm volatile("s_waitcnt vmcnt(4)" ::: "memory");
      asm volatile("s_barrier" ::: "memory");
    }
  }
  asm volatile("s_waitcnt vmcnt(0)" ::: "memory");

  float* db = dbuf + (size_t)ksplit * (size_t)NASSIGN * HD;
  const int crow = (lane >> 4) * 4, ccol = lane & 15;
  const int rbase = rt * 256 + wm * 128;
#pragma unroll
  for (int mt = 0; mt < 8; ++mt) {
#pragma unroll
    for (int j = 0; j < 4; ++j) {
      const int rl = rbase + mt * 16 + crow + j;
      if (rl >= cnt) continue;
      const size_t grow = (size_t)off + rl;
      const float wgt = pw[grow];
#pragma unroll
      for (int nt = 0; nt < 4; ++nt) {
        const int col = (int)bcol0 + wn * 64 + nt * 16 + ccol;
        db[grow * (size_t)HD + col] = acc[mt][nt][j] * wgt;
      }
    }
  }
}

// ---- combine: out[t] = dbuf0[p0]+dbuf0[p1]+dbuf1[p0]+dbuf1[p1] ----
__global__ __launch_bounds__(256) void k_combine(const float* __restrict__ dbuf,
    const int* __restrict__ inv, float* __restrict__ out) {
  const int t = blockIdx.x;
  const int p0 = inv[t * 2], p1 = inv[t * 2 + 1];
  const float* d1 = dbuf + (size_t)NASSIGN * HD;
  const float4* a0 = (const float4*)(dbuf + (size_t)p0 * HD);
  const float4* a1 = (const float4*)(dbuf + (size_t)p1 * HD);
  const float4* b0 = (const float4*)(d1 + (size_t)p0 * HD);
  const float4* b1 = (const float4*)(d1 + (size_t)p1 * HD);
  float4* o = (float4*)(out + (size_t)t * HD);
#pragma unroll
  for (int i = 0; i < 2; i++) {
    int c = threadIdx.x + i * 256;
    float4 x0 = a0[c], x1 = a1[c], y0 = b0[c], y1 = b1[c];
    o[c] = make_float4(x0.x + x1.x + y0.x + y1.x, x0.y + x1.y + y0.y + y1.y,
                       x0.z + x1.z + y0.z + y1.z, x0.w + x1.w + y0.w + y1.w);
  }
}

extern "C" void kernel_launch(void* const* d_in, const int* in_sizes, int n_in,
                              void* d_out, int out_size, void* d_ws, size_t ws_size,
                              hipStream_t stream) {
  const float* x  = (const float*)d_in[0];
  const float* rw = (const float*)d_in[1];
  const float* wg = (const float*)d_in[2];
  const float* wu = (const float*)d_in[3];
  const float* wd = (const float*)d_in[4];

  float* outp       = (float*)d_out;
  float* out_logits = outp + (size_t)NTOK * HD;
  float* out_topi   = out_logits + (size_t)NTOK * NE;
  float* out_topw   = out_topi + (size_t)NTOK * 2;

  char* w = (char*)d_ws;
  int*   cnts    = (int*)(w + 0);
  int*   offs    = (int*)(w + 64);
  int*   cursor  = (int*)(w + 128);
  int*   ntiles  = (int*)(w + 192);
  int*   tile_e  = (int*)(w + 256);
  int*   tile_rt = (int*)(w + 1280);
  int*   tk_e    = (int*)(w + 4096);
  float* tk_w    = (float*)(w + 4096 + 65536);
  int*   perm    = (int*)(w + 4096 + 2 * 65536);
  float* pw      = (float*)(w + 4096 + 3 * 65536);
  int*   inv     = (int*)(w + 4096 + 4 * 65536);

  char* big = w + (1 << 20);
  unsigned short* xg = (unsigned short*)big;                    // (NASSIGN+256) x HD
  const size_t XG_E = (size_t)(NASSIGN + 256) * HD;
  unsigned short* wgT = xg + XG_E;                              // [NE][ID][HD]
  const size_t WT_E = (size_t)NE * ID * HD;
  unsigned short* wuT  = wgT + WT_E;
  unsigned short* wdT  = wuT + WT_E;                            // [NE][HD][ID]
  unsigned short* gact = wdT + WT_E;                            // (NASSIGN+256) x ID
  const size_t GA_E = (size_t)(NASSIGN + 256) * ID;
  float* dbuf = (float*)(gact + GA_E);                          // 2 x NASSIGN x HD f32

  hipMemsetAsync(d_ws, 0, 256, stream);   // counters

  k_conv64<<<dim3(ID / 64, HD / 64, 2 * NE), 256, 0, stream>>>(
      wg, wu, wgT, wuT, HD, ID, 2);
  k_conv64<<<dim3(HD / 64, ID / 64, NE), 256, 0, stream>>>(
      wd, nullptr, wdT, nullptr, ID, HD, 1);

  k_router<<<NTOK / 4, 256, 0, stream>>>(x, rw, out_logits, out_topi, out_topw,
                                         tk_e, tk_w, cnts);
  k_scan<<<1, 64, 0, stream>>>(cnts, offs, cursor, tile_e, tile_rt, ntiles);
  k_assign<<<NTOK / 256, 256, 0, stream>>>(tk_e, tk_w, cursor, perm, pw, inv);
  k_gather<<<NASSIGN, 256, 0, stream>>>(x, perm, xg);

  // fused gate+up -> gact   (44 ct x 72 ti = 3168 blocks, %8==0)
  k_gemm_gu256f<<<dim3((ID / 128) * MAXT256), 512, 0, stream>>>(
      xg, wgT, wuT, cnts, offs, tile_e, tile_rt, ntiles, gact);
  // down (*pw) -> dbuf, K-split x2   (8 ct x 2 ks x 72 ti = 1152 blocks)
  k_gemm_dn256<<<dim3((HD / 256) * 2 * MAXT256), 512, 0, stream>>>(
      gact, wdT, cnts, offs, tile_e, tile_rt, ntiles, pw, dbuf);
  // out[t] = dbuf0[inv0]+dbuf0[inv1]+dbuf1[inv0]+dbuf1[inv1]
  k_combine<<<NTOK, 256, 0, stream>>>(dbuf, inv, outp);
}

// Round 15
// 1812.829 us; speedup vs baseline: 1.1005x; 1.0198x over previous
//
#include <hip/hip_runtime.h>
#include <hip/hip_bf16.h>
#include <stdint.h>

#define NTOK 8192
#define HD   2048
#define ID   5632
#define NE   8
#define NASSIGN (NTOK * 2)
#define MAXT256 (NASSIGN / 256 + NE)   // 72

typedef __attribute__((ext_vector_type(8))) short  bf16x8;
typedef __attribute__((ext_vector_type(4))) float  f32x4;
typedef __attribute__((ext_vector_type(8))) unsigned short u16x8;

__device__ __forceinline__ unsigned short f2bf(float f) {
  union { float f; unsigned int u; } c; c.f = f;
  unsigned int lsb = (c.u >> 16) & 1u;
  return (unsigned short)((c.u + 0x7fffu + lsb) >> 16);
}

__device__ __forceinline__ void async16(const void* g, void* l) {
  __builtin_amdgcn_global_load_lds(
      (const __attribute__((address_space(1))) void*)g,
      (__attribute__((address_space(3))) void*)l, 16, 0, 0);
}

// ---------------- router ----------------
__global__ __launch_bounds__(256) void k_router(
    const float* __restrict__ x, const float* __restrict__ rw,
    float* __restrict__ out_logits, float* __restrict__ out_topi,
    float* __restrict__ out_topw,
    int* __restrict__ tk_e, float* __restrict__ tk_w, int* __restrict__ cnts)
{
  const int wid = threadIdx.x >> 6, lane = threadIdx.x & 63;
  const int t = blockIdx.x * 4 + wid;
  const float* xr = x + (size_t)t * HD;
  float acc[NE];
#pragma unroll
  for (int e = 0; e < NE; e++) acc[e] = 0.f;
#pragma unroll
  for (int i = 0; i < 8; i++) {
    const int col = lane * 4 + i * 256;
    const float4 xv = *(const float4*)(xr + col);
#pragma unroll
    for (int e = 0; e < NE; e++) {
      const float4 wv = *(const float4*)(rw + e * HD + col);
      acc[e] += xv.x * wv.x + xv.y * wv.y + xv.z * wv.z + xv.w * wv.w;
    }
  }
#pragma unroll
  for (int e = 0; e < NE; e++)
    for (int o = 32; o >= 1; o >>= 1) acc[e] += __shfl_xor(acc[e], o, 64);

  if (lane == 0) {
    int i1 = 0;
#pragma unroll
    for (int e = 1; e < NE; e++) if (acc[e] > acc[i1]) i1 = e;
    int i2 = (i1 == 0) ? 1 : 0;
#pragma unroll
    for (int e = 0; e < NE; e++) if (e != i1 && acc[e] > acc[i2]) i2 = e;
    float p2 = __expf(acc[i2] - acc[i1]);
    float s  = 1.f + p2;
    float w1 = 1.f / s, w2 = p2 / s;
#pragma unroll
    for (int e = 0; e < NE; e++) out_logits[(size_t)t * NE + e] = acc[e];
    out_topi[t * 2 + 0] = (float)i1; out_topi[t * 2 + 1] = (float)i2;
    out_topw[t * 2 + 0] = w1;        out_topw[t * 2 + 1] = w2;
    tk_e[t * 2 + 0] = i1; tk_e[t * 2 + 1] = i2;
    tk_w[t * 2 + 0] = w1; tk_w[t * 2 + 1] = w2;
    atomicAdd(&cnts[i1], 1); atomicAdd(&cnts[i2], 1);
  }
}

__global__ void k_scan(const int* __restrict__ cnts, int* __restrict__ offs,
                       int* __restrict__ cursor, int* __restrict__ tile_e,
                       int* __restrict__ tile_rt, int* __restrict__ ntiles) {
  if (threadIdx.x == 0) {
    int s = 0, nt = 0;
    for (int e = 0; e < NE; e++) {
      offs[e] = s; cursor[e] = s;
      int ntl = (cnts[e] + 255) >> 8;
      for (int i = 0; i < ntl; i++) { tile_e[nt] = e; tile_rt[nt] = i; nt++; }
      s += cnts[e];
    }
    ntiles[0] = nt;
  }
}

__global__ void k_assign(const int* __restrict__ tk_e, const float* __restrict__ tk_w,
                         int* __restrict__ cursor, int* __restrict__ perm,
                         float* __restrict__ pw, int* __restrict__ inv) {
  int t = blockIdx.x * 256 + threadIdx.x;
  if (t >= NTOK) return;
#pragma unroll
  for (int k = 0; k < 2; k++) {
    int e = tk_e[t * 2 + k];
    int pos = atomicAdd(&cursor[e], 1);
    perm[pos] = t;
    pw[pos] = tk_w[t * 2 + k];
    inv[t * 2 + k] = pos;
  }
}

__global__ __launch_bounds__(256) void k_gather(const float* __restrict__ x,
    const int* __restrict__ perm, unsigned short* __restrict__ xg) {
  const int r = blockIdx.x;
  const int tok = perm[r];
  const float* src = x + (size_t)tok * HD;
  unsigned short* dst = xg + (size_t)r * HD;
  const int c = threadIdx.x * 8;
  float4 a = *(const float4*)(src + c);
  float4 b = *(const float4*)(src + c + 4);
  u16x8 o;
  o[0] = f2bf(a.x); o[1] = f2bf(a.y); o[2] = f2bf(a.z); o[3] = f2bf(a.w);
  o[4] = f2bf(b.x); o[5] = f2bf(b.y); o[6] = f2bf(b.z); o[7] = f2bf(b.w);
  *(u16x8*)(dst + c) = o;
}

// ---- transpose+convert: in fp32 [R][C] -> out bf16 [C][R], 64x64 tiles ----
__global__ __launch_bounds__(256) void k_conv64(const float* __restrict__ in0,
    const float* __restrict__ in1, unsigned short* __restrict__ out0,
    unsigned short* __restrict__ out1, int R, int C, int nmat) {
  __shared__ unsigned short tlb[64][72];   // row stride 144B
  const int z = blockIdx.z;
  const int mat = (nmat == 2) ? (z & 1) : 0;
  const int e   = (nmat == 2) ? (z >> 1) : z;
  const float* in = ((mat == 0) ? in0 : in1) + (size_t)e * R * C;
  unsigned short* out = ((mat == 0) ? out0 : out1) + (size_t)e * (size_t)R * C;
  const int tid = threadIdx.x;
  const int c0 = blockIdx.x * 64, r0 = blockIdx.y * 64;
#pragma unroll
  for (int pass = 0; pass < 4; ++pass) {
    const int kr = pass * 16 + (tid >> 4);
    const int cc = (tid & 15) * 4;
    const float4 v = *(const float4*)(in + (size_t)(r0 + kr) * C + c0 + cc);
    tlb[cc + 0][kr] = f2bf(v.x); tlb[cc + 1][kr] = f2bf(v.y);
    tlb[cc + 2][kr] = f2bf(v.z); tlb[cc + 3][kr] = f2bf(v.w);
  }
  __syncthreads();
#pragma unroll
  for (int pass = 0; pass < 2; ++pass) {
    const int n = pass * 32 + (tid >> 3);
    const int k = (tid & 7) * 8;
    *(u16x8*)(out + (size_t)(c0 + n) * R + r0 + k) = *(const u16x8*)&tlb[n][k];
  }
}

// ===== fused gate+up 256x(128+128) GEMM — single-barrier ring-4 pipeline =====
// R15: BK=32 steps, 4 x 32KB LDS ring (A 16K + Bg 8K + Bu 8K), stage distance
// 3 steps, ONE barrier per phase. Overwrite target is 2-3 barriers removed
// from its last read -> race-free; waves skew inside each barrier window so
// one wave's ds_reads overlap another's MFMA cluster (m114 mechanism).
// vmcnt(8) once per step (12 outstanding - 8 = the step's own 4 loads).
#define GBUF(b) ((b) * 32768)

__global__ __launch_bounds__(512, 2) void k_gemm_gu256f(
    const unsigned short* __restrict__ A,
    const unsigned short* __restrict__ BgT, const unsigned short* __restrict__ BuT,
    const int* __restrict__ cnts, const int* __restrict__ offs,
    const int* __restrict__ tile_e, const int* __restrict__ tile_rt,
    const int* __restrict__ ntiles, unsigned short* __restrict__ gact)
{
  const int raw = blockIdx.x;
  const int v = (raw & 7) * ((int)gridDim.x >> 3) + (raw >> 3);
  const int ct = v / MAXT256;            // [0,44)
  const int ti = v % MAXT256;
  if (ti >= ntiles[0]) return;
  const int e = tile_e[ti], rt = tile_rt[ti];
  const int cnt = cnts[e], off = offs[e];
  const int tid = threadIdx.x;

  __shared__ __align__(16) char smem[131072];

  const unsigned short* Bg = BgT + (size_t)e * (size_t)ID * HD;
  const unsigned short* Bu = BuT + (size_t)e * (size_t)ID * HD;
  const size_t arow0 = (size_t)off + (size_t)rt * 256;
  const size_t bcol0 = (size_t)ct * 128;

  const int r0s = tid >> 2;
  const int c0s = (((tid & 3) ^ ((tid >> 3) & 3)) * 8);

  const int NTS = HD / 32;   // 64 K-steps

  auto STAGE_A = [&](int bb, int kt) {
    const int kc = kt * 32;
    async16(A + (arow0 + r0s) * (size_t)HD + kc + c0s, smem + GBUF(bb) + tid * 16);
    async16(A + (arow0 + 128 + r0s) * (size_t)HD + kc + c0s, smem + GBUF(bb) + 8192 + tid * 16);
  };
  auto STAGE_B = [&](int bb, int kt) {
    const int kc = kt * 32;
    async16(Bg + (bcol0 + r0s) * (size_t)HD + kc + c0s, smem + GBUF(bb) + 16384 + tid * 16);
    async16(Bu + (bcol0 + r0s) * (size_t)HD + kc + c0s, smem + GBUF(bb) + 24576 + tid * 16);
  };

  f32x4 accg[8][2], accu[8][2];
#pragma unroll
  for (int m = 0; m < 8; m++)
#pragma unroll
    for (int n = 0; n < 2; n++) { accg[m][n] = (f32x4)0.f; accu[m][n] = (f32x4)0.f; }

  const int lane = tid & 63, wid = tid >> 6;
  const int wm = wid >> 2, wn = wid & 3;          // 2M x 4N
  const int fr = lane & 15;
  const int slot = ((lane >> 4) ^ ((fr >> 1) & 3));
  const int laddr = (fr << 6) + (slot << 4);

  // prologue: stage steps 0,1,2 into bufs 0,1,2 (12 loads, oldest-first)
  STAGE_A(0, 0); STAGE_B(0, 0);
  STAGE_A(1, 1); STAGE_B(1, 1);
  STAGE_A(2, 2); STAGE_B(2, 2);
  asm volatile("s_waitcnt vmcnt(8)" ::: "memory");   // step0's 4 loads done
  asm volatile("s_barrier" ::: "memory");

  bf16x8 bgr[2], bur[2];
  for (int s = 0; s < NTS; ++s) {
    const int bi = s & 3;
    char* base = smem + GBUF(bi);
    int sn = s + 3; sn = sn < NTS - 1 ? sn : NTS - 1;
    const int bn = (s + 3) & 3;
    // ---- phase mh0: reads A-lo + B, stage A(s+3), MFMA-lo, barrier ----
    asm volatile("s_waitcnt vmcnt(8)" ::: "memory");  // this step's buf ready
    {
      bf16x8 afr[4];
#pragma unroll
      for (int t = 0; t < 4; t++)
        afr[t] = *(const bf16x8*)(base + ((wm*128 + t*16) << 6) + laddr);
#pragma unroll
      for (int t = 0; t < 2; t++) {
        bgr[t] = *(const bf16x8*)(base + 16384 + ((wn*32 + t*16) << 6) + laddr);
        bur[t] = *(const bf16x8*)(base + 24576 + ((wn*32 + t*16) << 6) + laddr);
      }
      STAGE_A(bn, sn);
      __builtin_amdgcn_s_setprio(1);
#pragma unroll
      for (int t = 0; t < 4; t++)
#pragma unroll
        for (int n = 0; n < 2; n++) {
          accg[t][n] = __builtin_amdgcn_mfma_f32_16x16x32_bf16(afr[t], bgr[n], accg[t][n], 0, 0, 0);
          accu[t][n] = __builtin_amdgcn_mfma_f32_16x16x32_bf16(afr[t], bur[n], accu[t][n], 0, 0, 0);
        }
      __builtin_amdgcn_s_setprio(0);
    }
    asm volatile("s_barrier" ::: "memory");
    // ---- phase mh1: reads A-hi, stage B(s+3), MFMA-hi, barrier ----
    {
      bf16x8 afr[4];
#pragma unroll
      for (int t = 0; t < 4; t++)
        afr[t] = *(const bf16x8*)(base + ((wm*128 + 64 + t*16) << 6) + laddr);
      STAGE_B(bn, sn);
      __builtin_amdgcn_s_setprio(1);
#pragma unroll
      for (int t = 0; t < 4; t++)
#pragma unroll
        for (int n = 0; n < 2; n++) {
          accg[4 + t][n] = __builtin_amdgcn_mfma_f32_16x16x32_bf16(afr[t], bgr[n], accg[4 + t][n], 0, 0, 0);
          accu[4 + t][n] = __builtin_amdgcn_mfma_f32_16x16x32_bf16(afr[t], bur[n], accu[4 + t][n], 0, 0, 0);
        }
      __builtin_amdgcn_s_setprio(0);
    }
    asm volatile("s_barrier" ::: "memory");
  }
  asm volatile("s_waitcnt vmcnt(0)" ::: "memory");

  // epilogue: silu(g)*u -> gact; C/D map col=lane&15, row=(lane>>4)*4+j
  const int crow = (lane >> 4) * 4, ccol = lane & 15;
  const int rbase = rt * 256 + wm * 128;
#pragma unroll
  for (int mt = 0; mt < 8; ++mt) {
#pragma unroll
    for (int j = 0; j < 4; ++j) {
      const int rl = rbase + (mt & 3) * 16 + (mt >> 2) * 64 + crow + j;
      if (rl >= cnt) continue;
      const size_t grow = (size_t)off + rl;
#pragma unroll
      for (int nt = 0; nt < 2; ++nt) {
        const int col = (int)bcol0 + wn * 32 + nt * 16 + ccol;
        const float g = accg[(mt >> 2) * 4 + (mt & 3)][nt][j];
        const float u = accu[(mt >> 2) * 4 + (mt & 3)][nt][j];
        const float a = g / (1.f + __expf(-g)) * u;
        gact[grow * (size_t)ID + col] = f2bf(a);
      }
    }
  }
}

// ===== down 256x256 GEMM — single-barrier ring-4 + K-split x2 -> dbuf =====
__global__ __launch_bounds__(512, 2) void k_gemm_dn256(
    const unsigned short* __restrict__ A,     // gact [rows][ID]
    const unsigned short* __restrict__ Wbase, // [NE][HD][ID]
    const int* __restrict__ cnts, const int* __restrict__ offs,
    const int* __restrict__ tile_e, const int* __restrict__ tile_rt,
    const int* __restrict__ ntiles,
    const float* __restrict__ pw, float* __restrict__ dbuf)
{
  const int raw = blockIdx.x;
  const int v = (raw & 7) * ((int)gridDim.x >> 3) + (raw >> 3);
  const int ti = v % MAXT256;
  const int rest = v / MAXT256;          // [0,16)
  const int ksplit = rest & 1;
  const int ct = rest >> 1;              // [0,8)
  if (ti >= ntiles[0]) return;
  const int e = tile_e[ti], rt = tile_rt[ti];
  const int cnt = cnts[e], off = offs[e];
  const int tid = threadIdx.x;

  __shared__ __align__(16) char smem[131072];

  const unsigned short* W = Wbase + (size_t)e * (size_t)HD * ID;
  const size_t arow0 = (size_t)off + (size_t)rt * 256;
  const size_t bcol0 = (size_t)ct * 256;
  const int kbase = ksplit * (ID / 2);

  const int r0s = tid >> 2;
  const int c0s = (((tid & 3) ^ ((tid >> 3) & 3)) * 8);

  const int NTS = (ID / 2) / 32;   // 88 K-steps

  auto STAGE_A = [&](int bb, int kt) {
    const int kc = kbase + kt * 32;
    async16(A + (arow0 + r0s) * (size_t)ID + kc + c0s, smem + GBUF(bb) + tid * 16);
    async16(A + (arow0 + 128 + r0s) * (size_t)ID + kc + c0s, smem + GBUF(bb) + 8192 + tid * 16);
  };
  auto STAGE_B = [&](int bb, int kt) {
    const int kc = kbase + kt * 32;
    async16(W + (bcol0 + r0s) * (size_t)ID + kc + c0s, smem + GBUF(bb) + 16384 + tid * 16);
    async16(W + (bcol0 + 128 + r0s) * (size_t)ID + kc + c0s, smem + GBUF(bb) + 24576 + tid * 16);
  };

  f32x4 acc[8][4];
#pragma unroll
  for (int m = 0; m < 8; m++)
#pragma unroll
    for (int n = 0; n < 4; n++) acc[m][n] = (f32x4)0.f;

  const int lane = tid & 63, wid = tid >> 6;
  const int wm = wid >> 2, wn = wid & 3;
  const int fr = lane & 15;
  const int slot = ((lane >> 4) ^ ((fr >> 1) & 3));
  const int laddr = (fr << 6) + (slot << 4);

  STAGE_A(0, 0); STAGE_B(0, 0);
  STAGE_A(1, 1); STAGE_B(1, 1);
  STAGE_A(2, 2); STAGE_B(2, 2);
  asm volatile("s_waitcnt vmcnt(8)" ::: "memory");
  asm volatile("s_barrier" ::: "memory");

  bf16x8 bfr[4];
  for (int s = 0; s < NTS; ++s) {
    const int bi = s & 3;
    char* base = smem + GBUF(bi);
    int sn = s + 3; sn = sn < NTS - 1 ? sn : NTS - 1;
    const int bn = (s + 3) & 3;
    // ---- phase mh0 ----
    asm volatile("s_waitcnt vmcnt(8)" ::: "memory");
    {
      bf16x8 afr[4];
#pragma unroll
      for (int t = 0; t < 4; t++)
        afr[t] = *(const bf16x8*)(base + ((wm*128 + t*16) << 6) + laddr);
#pragma unroll
      for (int t = 0; t < 4; t++)
        bfr[t] = *(const bf16x8*)(base + 16384 + ((wn*64 + t*16) << 6) + laddr);
      STAGE_A(bn, sn);
      __builtin_amdgcn_s_setprio(1);
#pragma unroll
      for (int t = 0; t < 4; t++)
#pragma unroll
        for (int n = 0; n < 4; n++)
          acc[t][n] = __builtin_amdgcn_mfma_f32_16x16x32_bf16(afr[t], bfr[n], acc[t][n], 0, 0, 0);
      __builtin_amdgcn_s_setprio(0);
    }
    asm volatile("s_barrier" ::: "memory");
    // ---- phase mh1 ----
    {
      bf16x8 afr[4];
#pragma unroll
      for (int t = 0; t < 4; t++)
        afr[t] = *(const bf16x8*)(base + ((wm*128 + 64 + t*16) << 6) + laddr);
      STAGE_B(bn, sn);
      __builtin_amdgcn_s_setprio(1);
#pragma unroll
      for (int t = 0; t < 4; t++)
#pragma unroll
        for (int n = 0; n < 4; n++)
          acc[4 + t][n] = __builtin_amdgcn_mfma_f32_16x16x32_bf16(afr[t], bfr[n], acc[4 + t][n], 0, 0, 0);
      __builtin_amdgcn_s_setprio(0);
    }
    asm volatile("s_barrier" ::: "memory");
  }
  asm volatile("s_waitcnt vmcnt(0)" ::: "memory");

  float* db = dbuf + (size_t)ksplit * (size_t)NASSIGN * HD;
  const int crow = (lane >> 4) * 4, ccol = lane & 15;
  const int rbase = rt * 256 + wm * 128;
#pragma unroll
  for (int mt = 0; mt < 8; ++mt) {
#pragma unroll
    for (int j = 0; j < 4; ++j) {
      const int rl = rbase + (mt & 3) * 16 + (mt >> 2) * 64 + crow + j;
      if (rl >= cnt) continue;
      const size_t grow = (size_t)off + rl;
      const float wgt = pw[grow];
#pragma unroll
      for (int nt = 0; nt < 4; ++nt) {
        const int col = (int)bcol0 + wn * 64 + nt * 16 + ccol;
        db[grow * (size_t)HD + col] = acc[(mt >> 2) * 4 + (mt & 3)][nt][j] * wgt;
      }
    }
  }
}

// ---- combine: out[t] = dbuf0[p0]+dbuf0[p1]+dbuf1[p0]+dbuf1[p1] ----
__global__ __launch_bounds__(256) void k_combine(const float* __restrict__ dbuf,
    const int* __restrict__ inv, float* __restrict__ out) {
  const int t = blockIdx.x;
  const int p0 = inv[t * 2], p1 = inv[t * 2 + 1];
  const float* d1 = dbuf + (size_t)NASSIGN * HD;
  const float4* a0 = (const float4*)(dbuf + (size_t)p0 * HD);
  const float4* a1 = (const float4*)(dbuf + (size_t)p1 * HD);
  const float4* b0 = (const float4*)(d1 + (size_t)p0 * HD);
  const float4* b1 = (const float4*)(d1 + (size_t)p1 * HD);
  float4* o = (float4*)(out + (size_t)t * HD);
#pragma unroll
  for (int i = 0; i < 2; i++) {
    int c = threadIdx.x + i * 256;
    float4 x0 = a0[c], x1 = a1[c], y0 = b0[c], y1 = b1[c];
    o[c] = make_float4(x0.x + x1.x + y0.x + y1.x, x0.y + x1.y + y0.y + y1.y,
                       x0.z + x1.z + y0.z + y1.z, x0.w + x1.w + y0.w + y1.w);
  }
}

extern "C" void kernel_launch(void* const* d_in, const int* in_sizes, int n_in,
                              void* d_out, int out_size, void* d_ws, size_t ws_size,
                              hipStream_t stream) {
  const float* x  = (const float*)d_in[0];
  const float* rw = (const float*)d_in[1];
  const float* wg = (const float*)d_in[2];
  const float* wu = (const float*)d_in[3];
  const float* wd = (const float*)d_in[4];

  float* outp       = (float*)d_out;
  float* out_logits = outp + (size_t)NTOK * HD;
  float* out_topi   = out_logits + (size_t)NTOK * NE;
  float* out_topw   = out_topi + (size_t)NTOK * 2;

  char* w = (char*)d_ws;
  int*   cnts    = (int*)(w + 0);
  int*   offs    = (int*)(w + 64);
  int*   cursor  = (int*)(w + 128);
  int*   ntiles  = (int*)(w + 192);
  int*   tile_e  = (int*)(w + 256);
  int*   tile_rt = (int*)(w + 1280);
  int*   tk_e    = (int*)(w + 4096);
  float* tk_w    = (float*)(w + 4096 + 65536);
  int*   perm    = (int*)(w + 4096 + 2 * 65536);
  float* pw      = (float*)(w + 4096 + 3 * 65536);
  int*   inv     = (int*)(w + 4096 + 4 * 65536);

  char* big = w + (1 << 20);
  unsigned short* xg = (unsigned short*)big;                    // (NASSIGN+256) x HD
  const size_t XG_E = (size_t)(NASSIGN + 256) * HD;
  unsigned short* wgT = xg + XG_E;                              // [NE][ID][HD]
  const size_t WT_E = (size_t)NE * ID * HD;
  unsigned short* wuT  = wgT + WT_E;
  unsigned short* wdT  = wuT + WT_E;                            // [NE][HD][ID]
  unsigned short* gact = wdT + WT_E;                            // (NASSIGN+256) x ID
  const size_t GA_E = (size_t)(NASSIGN + 256) * ID;
  float* dbuf = (float*)(gact + GA_E);                          // 2 x NASSIGN x HD f32

  hipMemsetAsync(d_ws, 0, 256, stream);   // counters

  k_conv64<<<dim3(ID / 64, HD / 64, 2 * NE), 256, 0, stream>>>(
      wg, wu, wgT, wuT, HD, ID, 2);
  k_conv64<<<dim3(HD / 64, ID / 64, NE), 256, 0, stream>>>(
      wd, nullptr, wdT, nullptr, ID, HD, 1);

  k_router<<<NTOK / 4, 256, 0, stream>>>(x, rw, out_logits, out_topi, out_topw,
                                         tk_e, tk_w, cnts);
  k_scan<<<1, 64, 0, stream>>>(cnts, offs, cursor, tile_e, tile_rt, ntiles);
  k_assign<<<NTOK / 256, 256, 0, stream>>>(tk_e, tk_w, cursor, perm, pw, inv);
  k_gather<<<NASSIGN, 256, 0, stream>>>(x, perm, xg);

  // fused gate+up -> gact   (44 ct x 72 ti = 3168 blocks, %8==0)
  k_gemm_gu256f<<<dim3((ID / 128) * MAXT256), 512, 0, stream>>>(
      xg, wgT, wuT, cnts, offs, tile_e, tile_rt, ntiles, gact);
  // down (*pw) -> dbuf, K-split x2   (8 ct x 2 ks x 72 ti = 1152 blocks)
  k_gemm_dn256<<<dim3((HD / 256) * 2 * MAXT256), 512, 0, stream>>>(
      gact, wdT, cnts, offs, tile_e, tile_rt, ntiles, pw, dbuf);
  // out[t] = dbuf0[inv0]+dbuf0[inv1]+dbuf1[inv0]+dbuf1[inv1]
  k_combine<<<NTOK, 256, 0, stream>>>(dbuf, inv, outp);
}

// Round 16
// 1770.532 us; speedup vs baseline: 1.1268x; 1.0239x over previous
//
#include <hip/hip_runtime.h>
#include <hip/hip_bf16.h>
#include <stdint.h>

#define NTOK 8192
#define HD   2048
#define ID   5632
#define NE   8
#define NASSIGN (NTOK * 2)
#define MAXT256 (NASSIGN / 256 + NE)   // 72

#define NB_ROUTER 2048
#define NB_CONVGU (88 * 32 * 16)       // 45056
#define NB_CONVD  (32 * 88 * 8)        // 22528

typedef __attribute__((ext_vector_type(8))) short  bf16x8;
typedef __attribute__((ext_vector_type(4))) float  f32x4;
typedef __attribute__((ext_vector_type(8))) unsigned short u16x8;

__device__ __forceinline__ unsigned short f2bf(float f) {
  union { float f; unsigned int u; } c; c.f = f;
  unsigned int lsb = (c.u >> 16) & 1u;
  return (unsigned short)((c.u + 0x7fffu + lsb) >> 16);
}

__device__ __forceinline__ void async16(const void* g, void* l) {
  __builtin_amdgcn_global_load_lds(
      (const __attribute__((address_space(1))) void*)g,
      (__attribute__((address_space(3))) void*)l, 16, 0, 0);
}

// ---- transpose+convert body: in fp32 [R][C] -> out bf16 [C][R], 64x64 tile ----
__device__ __forceinline__ void conv_body(const float* in, unsigned short* out,
    int R, int C, int bx, int by, unsigned short (*tlb)[72]) {
  const int tid = threadIdx.x;
  const int c0 = bx * 64, r0 = by * 64;
#pragma unroll
  for (int pass = 0; pass < 4; ++pass) {
    const int kr = pass * 16 + (tid >> 4);
    const int cc = (tid & 15) * 4;
    const float4 v = *(const float4*)(in + (size_t)(r0 + kr) * C + c0 + cc);
    tlb[cc + 0][kr] = f2bf(v.x); tlb[cc + 1][kr] = f2bf(v.y);
    tlb[cc + 2][kr] = f2bf(v.z); tlb[cc + 3][kr] = f2bf(v.w);
  }
  __syncthreads();
#pragma unroll
  for (int pass = 0; pass < 2; ++pass) {
    const int n = pass * 32 + (tid >> 3);
    const int k = (tid & 7) * 8;
    *(u16x8*)(out + (size_t)(c0 + n) * R + r0 + k) = *(const u16x8*)&tlb[n][k];
  }
}

// ===== mega kernel: router + conv_gu + conv_d (independent work, one launch) =====
__global__ __launch_bounds__(256) void k_mega(
    const float* __restrict__ x, const float* __restrict__ rw,
    float* __restrict__ out_logits, float* __restrict__ out_topi,
    float* __restrict__ out_topw,
    int* __restrict__ tk_e, float* __restrict__ tk_w, int* __restrict__ cnts,
    const float* __restrict__ wg, const float* __restrict__ wu,
    const float* __restrict__ wd,
    unsigned short* __restrict__ wgT, unsigned short* __restrict__ wuT,
    unsigned short* __restrict__ wdT)
{
  __shared__ unsigned short tlb[64][72];
  int bid = blockIdx.x;

  if (bid < NB_ROUTER) {
    // ---------------- router ----------------
    const int wid = threadIdx.x >> 6, lane = threadIdx.x & 63;
    const int t = bid * 4 + wid;
    const float* xr = x + (size_t)t * HD;
    float acc[NE];
#pragma unroll
    for (int e = 0; e < NE; e++) acc[e] = 0.f;
#pragma unroll
    for (int i = 0; i < 8; i++) {
      const int col = lane * 4 + i * 256;
      const float4 xv = *(const float4*)(xr + col);
#pragma unroll
      for (int e = 0; e < NE; e++) {
        const float4 wv = *(const float4*)(rw + e * HD + col);
        acc[e] += xv.x * wv.x + xv.y * wv.y + xv.z * wv.z + xv.w * wv.w;
      }
    }
#pragma unroll
    for (int e = 0; e < NE; e++)
      for (int o = 32; o >= 1; o >>= 1) acc[e] += __shfl_xor(acc[e], o, 64);

    if (lane == 0) {
      int i1 = 0;
#pragma unroll
      for (int e = 1; e < NE; e++) if (acc[e] > acc[i1]) i1 = e;
      int i2 = (i1 == 0) ? 1 : 0;
#pragma unroll
      for (int e = 0; e < NE; e++) if (e != i1 && acc[e] > acc[i2]) i2 = e;
      float p2 = __expf(acc[i2] - acc[i1]);
      float s  = 1.f + p2;
      float w1 = 1.f / s, w2 = p2 / s;
#pragma unroll
      for (int e = 0; e < NE; e++) out_logits[(size_t)t * NE + e] = acc[e];
      out_topi[t * 2 + 0] = (float)i1; out_topi[t * 2 + 1] = (float)i2;
      out_topw[t * 2 + 0] = w1;        out_topw[t * 2 + 1] = w2;
      tk_e[t * 2 + 0] = i1; tk_e[t * 2 + 1] = i2;
      tk_w[t * 2 + 0] = w1; tk_w[t * 2 + 1] = w2;
      atomicAdd(&cnts[i1], 1); atomicAdd(&cnts[i2], 1);
    }
    return;
  }
  bid -= NB_ROUTER;
  if (bid < NB_CONVGU) {
    // conv gate/up: in [HD][ID] fp32 -> out [ID][HD] bf16, 16 matrices
    const int z = bid / (88 * 32);
    const int rem = bid % (88 * 32);
    const int by = rem / 88, bx = rem % 88;
    const int mat = z & 1, e = z >> 1;
    const float* in = ((mat == 0) ? wg : wu) + (size_t)e * HD * ID;
    unsigned short* out = ((mat == 0) ? wgT : wuT) + (size_t)e * (size_t)ID * HD;
    conv_body(in, out, HD, ID, bx, by, tlb);
    return;
  }
  bid -= NB_CONVGU;
  {
    // conv down: in [ID][HD] fp32 -> out [HD][ID] bf16, 8 matrices
    const int z = bid / (32 * 88);
    const int rem = bid % (32 * 88);
    const int by = rem / 32, bx = rem % 32;
    conv_body(wd + (size_t)z * ID * HD, wdT + (size_t)z * (size_t)HD * ID,
              ID, HD, bx, by, tlb);
  }
}

__global__ void k_scan(const int* __restrict__ cnts, int* __restrict__ offs,
                       int* __restrict__ cursor, int* __restrict__ tile_e,
                       int* __restrict__ tile_rt, int* __restrict__ ntiles) {
  if (threadIdx.x == 0) {
    int s = 0, nt = 0;
    for (int e = 0; e < NE; e++) {
      offs[e] = s; cursor[e] = s;
      int ntl = (cnts[e] + 255) >> 8;
      for (int i = 0; i < ntl; i++) { tile_e[nt] = e; tile_rt[nt] = i; nt++; }
      s += cnts[e];
    }
    ntiles[0] = nt;
  }
}

__global__ void k_assign(const int* __restrict__ tk_e, const float* __restrict__ tk_w,
                         int* __restrict__ cursor, int* __restrict__ perm,
                         float* __restrict__ pw, int* __restrict__ inv) {
  int t = blockIdx.x * 256 + threadIdx.x;
  if (t >= NTOK) return;
#pragma unroll
  for (int k = 0; k < 2; k++) {
    int e = tk_e[t * 2 + k];
    int pos = atomicAdd(&cursor[e], 1);
    perm[pos] = t;
    pw[pos] = tk_w[t * 2 + k];
    inv[t * 2 + k] = pos;
  }
}

__global__ __launch_bounds__(256) void k_gather(const float* __restrict__ x,
    const int* __restrict__ perm, unsigned short* __restrict__ xg) {
  const int r = blockIdx.x;
  const int tok = perm[r];
  const float* src = x + (size_t)tok * HD;
  unsigned short* dst = xg + (size_t)r * HD;
  const int c = threadIdx.x * 8;
  float4 a = *(const float4*)(src + c);
  float4 b = *(const float4*)(src + c + 4);
  u16x8 o;
  o[0] = f2bf(a.x); o[1] = f2bf(a.y); o[2] = f2bf(a.z); o[3] = f2bf(a.w);
  o[4] = f2bf(b.x); o[5] = f2bf(b.y); o[6] = f2bf(b.z); o[7] = f2bf(b.w);
  *(u16x8*)(dst + c) = o;
}

// ===== fused gate+up 256x(128+128) GEMM — single-barrier ring-4 (R15 verbatim) =====
#define GBUF(b) ((b) * 32768)

__global__ __launch_bounds__(512, 2) void k_gemm_gu256f(
    const unsigned short* __restrict__ A,
    const unsigned short* __restrict__ BgT, const unsigned short* __restrict__ BuT,
    const int* __restrict__ cnts, const int* __restrict__ offs,
    const int* __restrict__ tile_e, const int* __restrict__ tile_rt,
    const int* __restrict__ ntiles, unsigned short* __restrict__ gact)
{
  const int raw = blockIdx.x;
  const int v = (raw & 7) * ((int)gridDim.x >> 3) + (raw >> 3);
  const int ct = v / MAXT256;            // [0,44)
  const int ti = v % MAXT256;
  if (ti >= ntiles[0]) return;
  const int e = tile_e[ti], rt = tile_rt[ti];
  const int cnt = cnts[e], off = offs[e];
  const int tid = threadIdx.x;

  __shared__ __align__(16) char smem[131072];

  const unsigned short* Bg = BgT + (size_t)e * (size_t)ID * HD;
  const unsigned short* Bu = BuT + (size_t)e * (size_t)ID * HD;
  const size_t arow0 = (size_t)off + (size_t)rt * 256;
  const size_t bcol0 = (size_t)ct * 128;

  const int r0s = tid >> 2;
  const int c0s = (((tid & 3) ^ ((tid >> 3) & 3)) * 8);

  const int NTS = HD / 32;   // 64 K-steps

  auto STAGE_A = [&](int bb, int kt) {
    const int kc = kt * 32;
    async16(A + (arow0 + r0s) * (size_t)HD + kc + c0s, smem + GBUF(bb) + tid * 16);
    async16(A + (arow0 + 128 + r0s) * (size_t)HD + kc + c0s, smem + GBUF(bb) + 8192 + tid * 16);
  };
  auto STAGE_B = [&](int bb, int kt) {
    const int kc = kt * 32;
    async16(Bg + (bcol0 + r0s) * (size_t)HD + kc + c0s, smem + GBUF(bb) + 16384 + tid * 16);
    async16(Bu + (bcol0 + r0s) * (size_t)HD + kc + c0s, smem + GBUF(bb) + 24576 + tid * 16);
  };

  f32x4 accg[8][2], accu[8][2];
#pragma unroll
  for (int m = 0; m < 8; m++)
#pragma unroll
    for (int n = 0; n < 2; n++) { accg[m][n] = (f32x4)0.f; accu[m][n] = (f32x4)0.f; }

  const int lane = tid & 63, wid = tid >> 6;
  const int wm = wid >> 2, wn = wid & 3;          // 2M x 4N
  const int fr = lane & 15;
  const int slot = ((lane >> 4) ^ ((fr >> 1) & 3));
  const int laddr = (fr << 6) + (slot << 4);

  STAGE_A(0, 0); STAGE_B(0, 0);
  STAGE_A(1, 1); STAGE_B(1, 1);
  STAGE_A(2, 2); STAGE_B(2, 2);
  asm volatile("s_waitcnt vmcnt(8)" ::: "memory");
  asm volatile("s_barrier" ::: "memory");

  bf16x8 bgr[2], bur[2];
  for (int s = 0; s < NTS; ++s) {
    const int bi = s & 3;
    char* base = smem + GBUF(bi);
    int sn = s + 3; sn = sn < NTS - 1 ? sn : NTS - 1;
    const int bn = (s + 3) & 3;
    asm volatile("s_waitcnt vmcnt(8)" ::: "memory");
    {
      bf16x8 afr[4];
#pragma unroll
      for (int t = 0; t < 4; t++)
        afr[t] = *(const bf16x8*)(base + ((wm*128 + t*16) << 6) + laddr);
#pragma unroll
      for (int t = 0; t < 2; t++) {
        bgr[t] = *(const bf16x8*)(base + 16384 + ((wn*32 + t*16) << 6) + laddr);
        bur[t] = *(const bf16x8*)(base + 24576 + ((wn*32 + t*16) << 6) + laddr);
      }
      STAGE_A(bn, sn);
      __builtin_amdgcn_s_setprio(1);
#pragma unroll
      for (int t = 0; t < 4; t++)
#pragma unroll
        for (int n = 0; n < 2; n++) {
          accg[t][n] = __builtin_amdgcn_mfma_f32_16x16x32_bf16(afr[t], bgr[n], accg[t][n], 0, 0, 0);
          accu[t][n] = __builtin_amdgcn_mfma_f32_16x16x32_bf16(afr[t], bur[n], accu[t][n], 0, 0, 0);
        }
      __builtin_amdgcn_s_setprio(0);
    }
    asm volatile("s_barrier" ::: "memory");
    {
      bf16x8 afr[4];
#pragma unroll
      for (int t = 0; t < 4; t++)
        afr[t] = *(const bf16x8*)(base + ((wm*128 + 64 + t*16) << 6) + laddr);
      STAGE_B(bn, sn);
      __builtin_amdgcn_s_setprio(1);
#pragma unroll
      for (int t = 0; t < 4; t++)
#pragma unroll
        for (int n = 0; n < 2; n++) {
          accg[4 + t][n] = __builtin_amdgcn_mfma_f32_16x16x32_bf16(afr[t], bgr[n], accg[4 + t][n], 0, 0, 0);
          accu[4 + t][n] = __builtin_amdgcn_mfma_f32_16x16x32_bf16(afr[t], bur[n], accu[4 + t][n], 0, 0, 0);
        }
      __builtin_amdgcn_s_setprio(0);
    }
    asm volatile("s_barrier" ::: "memory");
  }
  asm volatile("s_waitcnt vmcnt(0)" ::: "memory");

  const int crow = (lane >> 4) * 4, ccol = lane & 15;
  const int rbase = rt * 256 + wm * 128;
#pragma unroll
  for (int mt = 0; mt < 8; ++mt) {
#pragma unroll
    for (int j = 0; j < 4; ++j) {
      const int rl = rbase + (mt & 3) * 16 + (mt >> 2) * 64 + crow + j;
      if (rl >= cnt) continue;
      const size_t grow = (size_t)off + rl;
#pragma unroll
      for (int nt = 0; nt < 2; ++nt) {
        const int col = (int)bcol0 + wn * 32 + nt * 16 + ccol;
        const float g = accg[(mt >> 2) * 4 + (mt & 3)][nt][j];
        const float u = accu[(mt >> 2) * 4 + (mt & 3)][nt][j];
        const float a = g / (1.f + __expf(-g)) * u;
        gact[grow * (size_t)ID + col] = f2bf(a);
      }
    }
  }
}

// ===== down 256x256 GEMM — single-barrier ring-4, full K (no split) -> dbuf =====
__global__ __launch_bounds__(512, 2) void k_gemm_dn256(
    const unsigned short* __restrict__ A,     // gact [rows][ID]
    const unsigned short* __restrict__ Wbase, // [NE][HD][ID]
    const int* __restrict__ cnts, const int* __restrict__ offs,
    const int* __restrict__ tile_e, const int* __restrict__ tile_rt,
    const int* __restrict__ ntiles,
    const float* __restrict__ pw, float* __restrict__ dbuf)
{
  const int raw = blockIdx.x;
  const int v = (raw & 7) * ((int)gridDim.x >> 3) + (raw >> 3);
  const int ct = v / MAXT256;            // [0,8)
  const int ti = v % MAXT256;
  if (ti >= ntiles[0]) return;
  const int e = tile_e[ti], rt = tile_rt[ti];
  const int cnt = cnts[e], off = offs[e];
  const int tid = threadIdx.x;

  __shared__ __align__(16) char smem[131072];

  const unsigned short* W = Wbase + (size_t)e * (size_t)HD * ID;
  const size_t arow0 = (size_t)off + (size_t)rt * 256;
  const size_t bcol0 = (size_t)ct * 256;

  const int r0s = tid >> 2;
  const int c0s = (((tid & 3) ^ ((tid >> 3) & 3)) * 8);

  const int NTS = ID / 32;   // 176 K-steps

  auto STAGE_A = [&](int bb, int kt) {
    const int kc = kt * 32;
    async16(A + (arow0 + r0s) * (size_t)ID + kc + c0s, smem + GBUF(bb) + tid * 16);
    async16(A + (arow0 + 128 + r0s) * (size_t)ID + kc + c0s, smem + GBUF(bb) + 8192 + tid * 16);
  };
  auto STAGE_B = [&](int bb, int kt) {
    const int kc = kt * 32;
    async16(W + (bcol0 + r0s) * (size_t)ID + kc + c0s, smem + GBUF(bb) + 16384 + tid * 16);
    async16(W + (bcol0 + 128 + r0s) * (size_t)ID + kc + c0s, smem + GBUF(bb) + 24576 + tid * 16);
  };

  f32x4 acc[8][4];
#pragma unroll
  for (int m = 0; m < 8; m++)
#pragma unroll
    for (int n = 0; n < 4; n++) acc[m][n] = (f32x4)0.f;

  const int lane = tid & 63, wid = tid >> 6;
  const int wm = wid >> 2, wn = wid & 3;
  const int fr = lane & 15;
  const int slot = ((lane >> 4) ^ ((fr >> 1) & 3));
  const int laddr = (fr << 6) + (slot << 4);

  STAGE_A(0, 0); STAGE_B(0, 0);
  STAGE_A(1, 1); STAGE_B(1, 1);
  STAGE_A(2, 2); STAGE_B(2, 2);
  asm volatile("s_waitcnt vmcnt(8)" ::: "memory");
  asm volatile("s_barrier" ::: "memory");

  bf16x8 bfr[4];
  for (int s = 0; s < NTS; ++s) {
    const int bi = s & 3;
    char* base = smem + GBUF(bi);
    int sn = s + 3; sn = sn < NTS - 1 ? sn : NTS - 1;
    const int bn = (s + 3) & 3;
    asm volatile("s_waitcnt vmcnt(8)" ::: "memory");
    {
      bf16x8 afr[4];
#pragma unroll
      for (int t = 0; t < 4; t++)
        afr[t] = *(const bf16x8*)(base + ((wm*128 + t*16) << 6) + laddr);
#pragma unroll
      for (int t = 0; t < 4; t++)
        bfr[t] = *(const bf16x8*)(base + 16384 + ((wn*64 + t*16) << 6) + laddr);
      STAGE_A(bn, sn);
      __builtin_amdgcn_s_setprio(1);
#pragma unroll
      for (int t = 0; t < 4; t++)
#pragma unroll
        for (int n = 0; n < 4; n++)
          acc[t][n] = __builtin_amdgcn_mfma_f32_16x16x32_bf16(afr[t], bfr[n], acc[t][n], 0, 0, 0);
      __builtin_amdgcn_s_setprio(0);
    }
    asm volatile("s_barrier" ::: "memory");
    {
      bf16x8 afr[4];
#pragma unroll
      for (int t = 0; t < 4; t++)
        afr[t] = *(const bf16x8*)(base + ((wm*128 + 64 + t*16) << 6) + laddr);
      STAGE_B(bn, sn);
      __builtin_amdgcn_s_setprio(1);
#pragma unroll
      for (int t = 0; t < 4; t++)
#pragma unroll
        for (int n = 0; n < 4; n++)
          acc[4 + t][n] = __builtin_amdgcn_mfma_f32_16x16x32_bf16(afr[t], bfr[n], acc[4 + t][n], 0, 0, 0);
      __builtin_amdgcn_s_setprio(0);
    }
    asm volatile("s_barrier" ::: "memory");
  }
  asm volatile("s_waitcnt vmcnt(0)" ::: "memory");

  const int crow = (lane >> 4) * 4, ccol = lane & 15;
  const int rbase = rt * 256 + wm * 128;
#pragma unroll
  for (int mt = 0; mt < 8; ++mt) {
#pragma unroll
    for (int j = 0; j < 4; ++j) {
      const int rl = rbase + (mt & 3) * 16 + (mt >> 2) * 64 + crow + j;
      if (rl >= cnt) continue;
      const size_t grow = (size_t)off + rl;
      const float wgt = pw[grow];
#pragma unroll
      for (int nt = 0; nt < 4; ++nt) {
        const int col = (int)bcol0 + wn * 64 + nt * 16 + ccol;
        dbuf[grow * (size_t)HD + col] = acc[(mt >> 2) * 4 + (mt & 3)][nt][j] * wgt;
      }
    }
  }
}

// -------- combine: out[t] = dbuf[inv[t,0]] + dbuf[inv[t,1]] --------
__global__ __launch_bounds__(256) void k_combine(const float* __restrict__ dbuf,
    const int* __restrict__ inv, float* __restrict__ out) {
  const int t = blockIdx.x;
  const int p0 = inv[t * 2], p1 = inv[t * 2 + 1];
  const float4* r0 = (const float4*)(dbuf + (size_t)p0 * HD);
  const float4* r1 = (const float4*)(dbuf + (size_t)p1 * HD);
  float4* o = (float4*)(out + (size_t)t * HD);
#pragma unroll
  for (int i = 0; i < 2; i++) {
    int c = threadIdx.x + i * 256;
    float4 a = r0[c], b = r1[c];
    o[c] = make_float4(a.x + b.x, a.y + b.y, a.z + b.z, a.w + b.w);
  }
}

extern "C" void kernel_launch(void* const* d_in, const int* in_sizes, int n_in,
                              void* d_out, int out_size, void* d_ws, size_t ws_size,
                              hipStream_t stream) {
  const float* x  = (const float*)d_in[0];
  const float* rw = (const float*)d_in[1];
  const float* wg = (const float*)d_in[2];
  const float* wu = (const float*)d_in[3];
  const float* wd = (const float*)d_in[4];

  float* outp       = (float*)d_out;
  float* out_logits = outp + (size_t)NTOK * HD;
  float* out_topi   = out_logits + (size_t)NTOK * NE;
  float* out_topw   = out_topi + (size_t)NTOK * 2;

  char* w = (char*)d_ws;
  int*   cnts    = (int*)(w + 0);
  int*   offs    = (int*)(w + 64);
  int*   cursor  = (int*)(w + 128);
  int*   ntiles  = (int*)(w + 192);
  int*   tile_e  = (int*)(w + 256);
  int*   tile_rt = (int*)(w + 1280);
  int*   tk_e    = (int*)(w + 4096);
  float* tk_w    = (float*)(w + 4096 + 65536);
  int*   perm    = (int*)(w + 4096 + 2 * 65536);
  float* pw      = (float*)(w + 4096 + 3 * 65536);
  int*   inv     = (int*)(w + 4096 + 4 * 65536);

  char* big = w + (1 << 20);
  unsigned short* xg = (unsigned short*)big;                    // (NASSIGN+256) x HD
  const size_t XG_E = (size_t)(NASSIGN + 256) * HD;
  unsigned short* wgT = xg + XG_E;                              // [NE][ID][HD]
  const size_t WT_E = (size_t)NE * ID * HD;
  unsigned short* wuT  = wgT + WT_E;
  unsigned short* wdT  = wuT + WT_E;                            // [NE][HD][ID]
  unsigned short* gact = wdT + WT_E;                            // (NASSIGN+256) x ID
  const size_t GA_E = (size_t)(NASSIGN + 256) * ID;
  float* dbuf = (float*)(gact + GA_E);                          // NASSIGN x HD f32

  hipMemsetAsync(d_ws, 0, 256, stream);   // counters

  // router + conv_gu + conv_d in one launch (all mutually independent)
  k_mega<<<NB_ROUTER + NB_CONVGU + NB_CONVD, 256, 0, stream>>>(
      x, rw, out_logits, out_topi, out_topw, tk_e, tk_w, cnts,
      wg, wu, wd, wgT, wuT, wdT);

  k_scan<<<1, 64, 0, stream>>>(cnts, offs, cursor, tile_e, tile_rt, ntiles);
  k_assign<<<NTOK / 256, 256, 0, stream>>>(tk_e, tk_w, cursor, perm, pw, inv);
  k_gather<<<NASSIGN, 256, 0, stream>>>(x, perm, xg);

  // fused gate+up -> gact   (44 ct x 72 ti = 3168 blocks, %8==0)
  k_gemm_gu256f<<<dim3((ID / 128) * MAXT256), 512, 0, stream>>>(
      xg, wgT, wuT, cnts, offs, tile_e, tile_rt, ntiles, gact);
  // down (*pw) -> dbuf   (8 ct x 72 ti = 576 blocks)
  k_gemm_dn256<<<dim3((HD / 256) * MAXT256), 512, 0, stream>>>(
      gact, wdT, cnts, offs, tile_e, tile_rt, ntiles, pw, dbuf);
  // out[t] = dbuf[inv0] + dbuf[inv1]
  k_combine<<<NTOK, 256, 0, stream>>>(dbuf, inv, outp);
}

// Round 17
// 1719.954 us; speedup vs baseline: 1.1599x; 1.0294x over previous
//
#include <hip/hip_runtime.h>
#include <hip/hip_bf16.h>
#include <stdint.h>

#define NTOK 8192
#define HD   2048
#define ID   5632
#define NE   8
#define NASSIGN (NTOK * 2)
#define MAXT256 (NASSIGN / 256 + NE)   // 72

#define NB_ROUTER 2048
#define NB_CONVGU (88 * 32 * 16)       // 45056
#define NB_CONVD  (32 * 88 * 8)        // 22528

typedef __attribute__((ext_vector_type(8))) short  bf16x8;
typedef __attribute__((ext_vector_type(4))) float  f32x4;
typedef __attribute__((ext_vector_type(8))) unsigned short u16x8;
typedef __attribute__((ext_vector_type(4))) unsigned short u16x4;

__device__ __forceinline__ unsigned short f2bf(float f) {
  union { float f; unsigned int u; } c; c.f = f;
  unsigned int lsb = (c.u >> 16) & 1u;
  return (unsigned short)((c.u + 0x7fffu + lsb) >> 16);
}
__device__ __forceinline__ float bf2f(unsigned short u) {
  union { float f; unsigned int u; } c; c.u = ((unsigned int)u) << 16;
  return c.f;
}

__device__ __forceinline__ void async16(const void* g, void* l) {
  __builtin_amdgcn_global_load_lds(
      (const __attribute__((address_space(1))) void*)g,
      (__attribute__((address_space(3))) void*)l, 16, 0, 0);
}

// ---- transpose+convert body: in fp32 [R][C] -> out bf16 [C][R], 64x64 tile ----
__device__ __forceinline__ void conv_body(const float* in, unsigned short* out,
    int R, int C, int bx, int by, unsigned short (*tlb)[72]) {
  const int tid = threadIdx.x;
  const int c0 = bx * 64, r0 = by * 64;
#pragma unroll
  for (int pass = 0; pass < 4; ++pass) {
    const int kr = pass * 16 + (tid >> 4);
    const int cc = (tid & 15) * 4;
    const float4 v = *(const float4*)(in + (size_t)(r0 + kr) * C + c0 + cc);
    tlb[cc + 0][kr] = f2bf(v.x); tlb[cc + 1][kr] = f2bf(v.y);
    tlb[cc + 2][kr] = f2bf(v.z); tlb[cc + 3][kr] = f2bf(v.w);
  }
  __syncthreads();
#pragma unroll
  for (int pass = 0; pass < 2; ++pass) {
    const int n = pass * 32 + (tid >> 3);
    const int k = (tid & 7) * 8;
    *(u16x8*)(out + (size_t)(c0 + n) * R + r0 + k) = *(const u16x8*)&tlb[n][k];
  }
}

// ===== mega kernel: router + conv_gu + conv_d (independent work, one launch) =====
__global__ __launch_bounds__(256) void k_mega(
    const float* __restrict__ x, const float* __restrict__ rw,
    float* __restrict__ out_logits, float* __restrict__ out_topi,
    float* __restrict__ out_topw,
    int* __restrict__ tk_e, float* __restrict__ tk_w, int* __restrict__ cnts,
    const float* __restrict__ wg, const float* __restrict__ wu,
    const float* __restrict__ wd,
    unsigned short* __restrict__ wgT, unsigned short* __restrict__ wuT,
    unsigned short* __restrict__ wdT)
{
  __shared__ unsigned short tlb[64][72];
  int bid = blockIdx.x;

  if (bid < NB_ROUTER) {
    const int wid = threadIdx.x >> 6, lane = threadIdx.x & 63;
    const int t = bid * 4 + wid;
    const float* xr = x + (size_t)t * HD;
    float acc[NE];
#pragma unroll
    for (int e = 0; e < NE; e++) acc[e] = 0.f;
#pragma unroll
    for (int i = 0; i < 8; i++) {
      const int col = lane * 4 + i * 256;
      const float4 xv = *(const float4*)(xr + col);
#pragma unroll
      for (int e = 0; e < NE; e++) {
        const float4 wv = *(const float4*)(rw + e * HD + col);
        acc[e] += xv.x * wv.x + xv.y * wv.y + xv.z * wv.z + xv.w * wv.w;
      }
    }
#pragma unroll
    for (int e = 0; e < NE; e++)
      for (int o = 32; o >= 1; o >>= 1) acc[e] += __shfl_xor(acc[e], o, 64);

    if (lane == 0) {
      int i1 = 0;
#pragma unroll
      for (int e = 1; e < NE; e++) if (acc[e] > acc[i1]) i1 = e;
      int i2 = (i1 == 0) ? 1 : 0;
#pragma unroll
      for (int e = 0; e < NE; e++) if (e != i1 && acc[e] > acc[i2]) i2 = e;
      float p2 = __expf(acc[i2] - acc[i1]);
      float s  = 1.f + p2;
      float w1 = 1.f / s, w2 = p2 / s;
#pragma unroll
      for (int e = 0; e < NE; e++) out_logits[(size_t)t * NE + e] = acc[e];
      out_topi[t * 2 + 0] = (float)i1; out_topi[t * 2 + 1] = (float)i2;
      out_topw[t * 2 + 0] = w1;        out_topw[t * 2 + 1] = w2;
      tk_e[t * 2 + 0] = i1; tk_e[t * 2 + 1] = i2;
      tk_w[t * 2 + 0] = w1; tk_w[t * 2 + 1] = w2;
      atomicAdd(&cnts[i1], 1); atomicAdd(&cnts[i2], 1);
    }
    return;
  }
  bid -= NB_ROUTER;
  if (bid < NB_CONVGU) {
    const int z = bid / (88 * 32);
    const int rem = bid % (88 * 32);
    const int by = rem / 88, bx = rem % 88;
    const int mat = z & 1, e = z >> 1;
    const float* in = ((mat == 0) ? wg : wu) + (size_t)e * HD * ID;
    unsigned short* out = ((mat == 0) ? wgT : wuT) + (size_t)e * (size_t)ID * HD;
    conv_body(in, out, HD, ID, bx, by, tlb);
    return;
  }
  bid -= NB_CONVGU;
  {
    const int z = bid / (32 * 88);
    const int rem = bid % (32 * 88);
    const int by = rem / 32, bx = rem % 32;
    conv_body(wd + (size_t)z * ID * HD, wdT + (size_t)z * (size_t)HD * ID,
              ID, HD, bx, by, tlb);
  }
}

// ===== scan + assign fused: single block, LDS cursors =====
__global__ __launch_bounds__(256) void k_scanassign(
    const int* __restrict__ cnts, const int* __restrict__ tk_e,
    const float* __restrict__ tk_w,
    int* __restrict__ offs_g, int* __restrict__ tile_e,
    int* __restrict__ tile_rt, int* __restrict__ ntiles,
    int* __restrict__ perm, float* __restrict__ pw, int* __restrict__ inv)
{
  __shared__ int cur[NE];
  __shared__ int offs[NE];
  if (threadIdx.x == 0) {
    int s = 0, nt = 0;
    for (int e = 0; e < NE; e++) {
      offs[e] = s; cur[e] = s; offs_g[e] = s;
      int ntl = (cnts[e] + 255) >> 8;
      for (int i = 0; i < ntl; i++) { tile_e[nt] = e; tile_rt[nt] = i; nt++; }
      s += cnts[e];
    }
    ntiles[0] = nt;
  }
  __syncthreads();
  for (int t = threadIdx.x; t < NTOK; t += 256) {
#pragma unroll
    for (int k = 0; k < 2; k++) {
      int e = tk_e[t * 2 + k];
      int pos = atomicAdd(&cur[e], 1);
      perm[pos] = t;
      pw[pos] = tk_w[t * 2 + k];
      inv[t * 2 + k] = pos;
    }
  }
}

__global__ __launch_bounds__(256) void k_gather(const float* __restrict__ x,
    const int* __restrict__ perm, unsigned short* __restrict__ xg) {
  const int r = blockIdx.x;
  const int tok = perm[r];
  const float* src = x + (size_t)tok * HD;
  unsigned short* dst = xg + (size_t)r * HD;
  const int c = threadIdx.x * 8;
  float4 a = *(const float4*)(src + c);
  float4 b = *(const float4*)(src + c + 4);
  u16x8 o;
  o[0] = f2bf(a.x); o[1] = f2bf(a.y); o[2] = f2bf(a.z); o[3] = f2bf(a.w);
  o[4] = f2bf(b.x); o[5] = f2bf(b.y); o[6] = f2bf(b.z); o[7] = f2bf(b.w);
  *(u16x8*)(dst + c) = o;
}

// ===== fused gate+up 256x(128+128) GEMM — single-barrier ring-4 (R15 verbatim) =====
#define GBUF(b) ((b) * 32768)

__global__ __launch_bounds__(512, 2) void k_gemm_gu256f(
    const unsigned short* __restrict__ A,
    const unsigned short* __restrict__ BgT, const unsigned short* __restrict__ BuT,
    const int* __restrict__ cnts, const int* __restrict__ offs,
    const int* __restrict__ tile_e, const int* __restrict__ tile_rt,
    const int* __restrict__ ntiles, unsigned short* __restrict__ gact)
{
  const int raw = blockIdx.x;
  const int v = (raw & 7) * ((int)gridDim.x >> 3) + (raw >> 3);
  const int ct = v / MAXT256;            // [0,44)
  const int ti = v % MAXT256;
  if (ti >= ntiles[0]) return;
  const int e = tile_e[ti], rt = tile_rt[ti];
  const int cnt = cnts[e], off = offs[e];
  const int tid = threadIdx.x;

  __shared__ __align__(16) char smem[131072];

  const unsigned short* Bg = BgT + (size_t)e * (size_t)ID * HD;
  const unsigned short* Bu = BuT + (size_t)e * (size_t)ID * HD;
  const size_t arow0 = (size_t)off + (size_t)rt * 256;
  const size_t bcol0 = (size_t)ct * 128;

  const int r0s = tid >> 2;
  const int c0s = (((tid & 3) ^ ((tid >> 3) & 3)) * 8);

  const int NTS = HD / 32;   // 64 K-steps

  auto STAGE_A = [&](int bb, int kt) {
    const int kc = kt * 32;
    async16(A + (arow0 + r0s) * (size_t)HD + kc + c0s, smem + GBUF(bb) + tid * 16);
    async16(A + (arow0 + 128 + r0s) * (size_t)HD + kc + c0s, smem + GBUF(bb) + 8192 + tid * 16);
  };
  auto STAGE_B = [&](int bb, int kt) {
    const int kc = kt * 32;
    async16(Bg + (bcol0 + r0s) * (size_t)HD + kc + c0s, smem + GBUF(bb) + 16384 + tid * 16);
    async16(Bu + (bcol0 + r0s) * (size_t)HD + kc + c0s, smem + GBUF(bb) + 24576 + tid * 16);
  };

  f32x4 accg[8][2], accu[8][2];
#pragma unroll
  for (int m = 0; m < 8; m++)
#pragma unroll
    for (int n = 0; n < 2; n++) { accg[m][n] = (f32x4)0.f; accu[m][n] = (f32x4)0.f; }

  const int lane = tid & 63, wid = tid >> 6;
  const int wm = wid >> 2, wn = wid & 3;          // 2M x 4N
  const int fr = lane & 15;
  const int slot = ((lane >> 4) ^ ((fr >> 1) & 3));
  const int laddr = (fr << 6) + (slot << 4);

  STAGE_A(0, 0); STAGE_B(0, 0);
  STAGE_A(1, 1); STAGE_B(1, 1);
  STAGE_A(2, 2); STAGE_B(2, 2);
  asm volatile("s_waitcnt vmcnt(8)" ::: "memory");
  asm volatile("s_barrier" ::: "memory");

  bf16x8 bgr[2], bur[2];
  for (int s = 0; s < NTS; ++s) {
    const int bi = s & 3;
    char* base = smem + GBUF(bi);
    int sn = s + 3; sn = sn < NTS - 1 ? sn : NTS - 1;
    const int bn = (s + 3) & 3;
    asm volatile("s_waitcnt vmcnt(8)" ::: "memory");
    {
      bf16x8 afr[4];
#pragma unroll
      for (int t = 0; t < 4; t++)
        afr[t] = *(const bf16x8*)(base + ((wm*128 + t*16) << 6) + laddr);
#pragma unroll
      for (int t = 0; t < 2; t++) {
        bgr[t] = *(const bf16x8*)(base + 16384 + ((wn*32 + t*16) << 6) + laddr);
        bur[t] = *(const bf16x8*)(base + 24576 + ((wn*32 + t*16) << 6) + laddr);
      }
      STAGE_A(bn, sn);
      __builtin_amdgcn_s_setprio(1);
#pragma unroll
      for (int t = 0; t < 4; t++)
#pragma unroll
        for (int n = 0; n < 2; n++) {
          accg[t][n] = __builtin_amdgcn_mfma_f32_16x16x32_bf16(afr[t], bgr[n], accg[t][n], 0, 0, 0);
          accu[t][n] = __builtin_amdgcn_mfma_f32_16x16x32_bf16(afr[t], bur[n], accu[t][n], 0, 0, 0);
        }
      __builtin_amdgcn_s_setprio(0);
    }
    asm volatile("s_barrier" ::: "memory");
    {
      bf16x8 afr[4];
#pragma unroll
      for (int t = 0; t < 4; t++)
        afr[t] = *(const bf16x8*)(base + ((wm*128 + 64 + t*16) << 6) + laddr);
      STAGE_B(bn, sn);
      __builtin_amdgcn_s_setprio(1);
#pragma unroll
      for (int t = 0; t < 4; t++)
#pragma unroll
        for (int n = 0; n < 2; n++) {
          accg[4 + t][n] = __builtin_amdgcn_mfma_f32_16x16x32_bf16(afr[t], bgr[n], accg[4 + t][n], 0, 0, 0);
          accu[4 + t][n] = __builtin_amdgcn_mfma_f32_16x16x32_bf16(afr[t], bur[n], accu[4 + t][n], 0, 0, 0);
        }
      __builtin_amdgcn_s_setprio(0);
    }
    asm volatile("s_barrier" ::: "memory");
  }
  asm volatile("s_waitcnt vmcnt(0)" ::: "memory");

  const int crow = (lane >> 4) * 4, ccol = lane & 15;
  const int rbase = rt * 256 + wm * 128;
#pragma unroll
  for (int mt = 0; mt < 8; ++mt) {
#pragma unroll
    for (int j = 0; j < 4; ++j) {
      const int rl = rbase + (mt & 3) * 16 + (mt >> 2) * 64 + crow + j;
      if (rl >= cnt) continue;
      const size_t grow = (size_t)off + rl;
#pragma unroll
      for (int nt = 0; nt < 2; ++nt) {
        const int col = (int)bcol0 + wn * 32 + nt * 16 + ccol;
        const float g = accg[(mt >> 2) * 4 + (mt & 3)][nt][j];
        const float u = accu[(mt >> 2) * 4 + (mt & 3)][nt][j];
        const float a = g / (1.f + __expf(-g)) * u;
        gact[grow * (size_t)ID + col] = f2bf(a);
      }
    }
  }
}

// ===== down 256x256 GEMM — single-barrier ring-4 -> dbuf (bf16) =====
__global__ __launch_bounds__(512, 2) void k_gemm_dn256(
    const unsigned short* __restrict__ A,     // gact [rows][ID]
    const unsigned short* __restrict__ Wbase, // [NE][HD][ID]
    const int* __restrict__ cnts, const int* __restrict__ offs,
    const int* __restrict__ tile_e, const int* __restrict__ tile_rt,
    const int* __restrict__ ntiles,
    const float* __restrict__ pw, unsigned short* __restrict__ dbuf)
{
  const int raw = blockIdx.x;
  const int v = (raw & 7) * ((int)gridDim.x >> 3) + (raw >> 3);
  const int ct = v / MAXT256;            // [0,8)
  const int ti = v % MAXT256;
  if (ti >= ntiles[0]) return;
  const int e = tile_e[ti], rt = tile_rt[ti];
  const int cnt = cnts[e], off = offs[e];
  const int tid = threadIdx.x;

  __shared__ __align__(16) char smem[131072];

  const unsigned short* W = Wbase + (size_t)e * (size_t)HD * ID;
  const size_t arow0 = (size_t)off + (size_t)rt * 256;
  const size_t bcol0 = (size_t)ct * 256;

  const int r0s = tid >> 2;
  const int c0s = (((tid & 3) ^ ((tid >> 3) & 3)) * 8);

  const int NTS = ID / 32;   // 176 K-steps

  auto STAGE_A = [&](int bb, int kt) {
    const int kc = kt * 32;
    async16(A + (arow0 + r0s) * (size_t)ID + kc + c0s, smem + GBUF(bb) + tid * 16);
    async16(A + (arow0 + 128 + r0s) * (size_t)ID + kc + c0s, smem + GBUF(bb) + 8192 + tid * 16);
  };
  auto STAGE_B = [&](int bb, int kt) {
    const int kc = kt * 32;
    async16(W + (bcol0 + r0s) * (size_t)ID + kc + c0s, smem + GBUF(bb) + 16384 + tid * 16);
    async16(W + (bcol0 + 128 + r0s) * (size_t)ID + kc + c0s, smem + GBUF(bb) + 24576 + tid * 16);
  };

  f32x4 acc[8][4];
#pragma unroll
  for (int m = 0; m < 8; m++)
#pragma unroll
    for (int n = 0; n < 4; n++) acc[m][n] = (f32x4)0.f;

  const int lane = tid & 63, wid = tid >> 6;
  const int wm = wid >> 2, wn = wid & 3;
  const int fr = lane & 15;
  const int slot = ((lane >> 4) ^ ((fr >> 1) & 3));
  const int laddr = (fr << 6) + (slot << 4);

  STAGE_A(0, 0); STAGE_B(0, 0);
  STAGE_A(1, 1); STAGE_B(1, 1);
  STAGE_A(2, 2); STAGE_B(2, 2);
  asm volatile("s_waitcnt vmcnt(8)" ::: "memory");
  asm volatile("s_barrier" ::: "memory");

  bf16x8 bfr[4];
  for (int s = 0; s < NTS; ++s) {
    const int bi = s & 3;
    char* base = smem + GBUF(bi);
    int sn = s + 3; sn = sn < NTS - 1 ? sn : NTS - 1;
    const int bn = (s + 3) & 3;
    asm volatile("s_waitcnt vmcnt(8)" ::: "memory");
    {
      bf16x8 afr[4];
#pragma unroll
      for (int t = 0; t < 4; t++)
        afr[t] = *(const bf16x8*)(base + ((wm*128 + t*16) << 6) + laddr);
#pragma unroll
      for (int t = 0; t < 4; t++)
        bfr[t] = *(const bf16x8*)(base + 16384 + ((wn*64 + t*16) << 6) + laddr);
      STAGE_A(bn, sn);
      __builtin_amdgcn_s_setprio(1);
#pragma unroll
      for (int t = 0; t < 4; t++)
#pragma unroll
        for (int n = 0; n < 4; n++)
          acc[t][n] = __builtin_amdgcn_mfma_f32_16x16x32_bf16(afr[t], bfr[n], acc[t][n], 0, 0, 0);
      __builtin_amdgcn_s_setprio(0);
    }
    asm volatile("s_barrier" ::: "memory");
    {
      bf16x8 afr[4];
#pragma unroll
      for (int t = 0; t < 4; t++)
        afr[t] = *(const bf16x8*)(base + ((wm*128 + 64 + t*16) << 6) + laddr);
      STAGE_B(bn, sn);
      __builtin_amdgcn_s_setprio(1);
#pragma unroll
      for (int t = 0; t < 4; t++)
#pragma unroll
        for (int n = 0; n < 4; n++)
          acc[4 + t][n] = __builtin_amdgcn_mfma_f32_16x16x32_bf16(afr[t], bfr[n], acc[4 + t][n], 0, 0, 0);
      __builtin_amdgcn_s_setprio(0);
    }
    asm volatile("s_barrier" ::: "memory");
  }
  asm volatile("s_waitcnt vmcnt(0)" ::: "memory");

  const int crow = (lane >> 4) * 4, ccol = lane & 15;
  const int rbase = rt * 256 + wm * 128;
#pragma unroll
  for (int mt = 0; mt < 8; ++mt) {
#pragma unroll
    for (int j = 0; j < 4; ++j) {
      const int rl = rbase + (mt & 3) * 16 + (mt >> 2) * 64 + crow + j;
      if (rl >= cnt) continue;
      const size_t grow = (size_t)off + rl;
      const float wgt = pw[grow];
#pragma unroll
      for (int nt = 0; nt < 4; ++nt) {
        const int col = (int)bcol0 + wn * 64 + nt * 16 + ccol;
        dbuf[grow * (size_t)HD + col] = f2bf(acc[(mt >> 2) * 4 + (mt & 3)][nt][j] * wgt);
      }
    }
  }
}

// -------- combine: out[t] = dbuf[inv[t,0]] + dbuf[inv[t,1]]  (bf16 in, f32 out) --------
__global__ __launch_bounds__(256) void k_combine(const unsigned short* __restrict__ dbuf,
    const int* __restrict__ inv, float* __restrict__ out) {
  const int t = blockIdx.x;
  const int p0 = inv[t * 2], p1 = inv[t * 2 + 1];
  const unsigned short* r0 = dbuf + (size_t)p0 * HD;
  const unsigned short* r1 = dbuf + (size_t)p1 * HD;
  float* o = out + (size_t)t * HD;
  const int c = threadIdx.x * 8;
  u16x8 a = *(const u16x8*)(r0 + c);
  u16x8 b = *(const u16x8*)(r1 + c);
  float4 o0, o1;
  o0.x = bf2f(a[0]) + bf2f(b[0]); o0.y = bf2f(a[1]) + bf2f(b[1]);
  o0.z = bf2f(a[2]) + bf2f(b[2]); o0.w = bf2f(a[3]) + bf2f(b[3]);
  o1.x = bf2f(a[4]) + bf2f(b[4]); o1.y = bf2f(a[5]) + bf2f(b[5]);
  o1.z = bf2f(a[6]) + bf2f(b[6]); o1.w = bf2f(a[7]) + bf2f(b[7]);
  *(float4*)(o + c) = o0;
  *(float4*)(o + c + 4) = o1;
}

extern "C" void kernel_launch(void* const* d_in, const int* in_sizes, int n_in,
                              void* d_out, int out_size, void* d_ws, size_t ws_size,
                              hipStream_t stream) {
  const float* x  = (const float*)d_in[0];
  const float* rw = (const float*)d_in[1];
  const float* wg = (const float*)d_in[2];
  const float* wu = (const float*)d_in[3];
  const float* wd = (const float*)d_in[4];

  float* outp       = (float*)d_out;
  float* out_logits = outp + (size_t)NTOK * HD;
  float* out_topi   = out_logits + (size_t)NTOK * NE;
  float* out_topw   = out_topi + (size_t)NTOK * 2;

  char* w = (char*)d_ws;
  int*   cnts    = (int*)(w + 0);
  int*   offs    = (int*)(w + 64);
  int*   ntiles  = (int*)(w + 192);
  int*   tile_e  = (int*)(w + 256);
  int*   tile_rt = (int*)(w + 1280);
  int*   tk_e    = (int*)(w + 4096);
  float* tk_w    = (float*)(w + 4096 + 65536);
  int*   perm    = (int*)(w + 4096 + 2 * 65536);
  float* pw      = (float*)(w + 4096 + 3 * 65536);
  int*   inv     = (int*)(w + 4096 + 4 * 65536);

  char* big = w + (1 << 20);
  unsigned short* xg = (unsigned short*)big;                    // (NASSIGN+256) x HD
  const size_t XG_E = (size_t)(NASSIGN + 256) * HD;
  unsigned short* wgT = xg + XG_E;                              // [NE][ID][HD]
  const size_t WT_E = (size_t)NE * ID * HD;
  unsigned short* wuT  = wgT + WT_E;
  unsigned short* wdT  = wuT + WT_E;                            // [NE][HD][ID]
  unsigned short* gact = wdT + WT_E;                            // (NASSIGN+256) x ID
  const size_t GA_E = (size_t)(NASSIGN + 256) * ID;
  unsigned short* dbuf = gact + GA_E;                           // NASSIGN x HD bf16

  hipMemsetAsync(d_ws, 0, 256, stream);   // counters

  // router + conv_gu + conv_d in one launch (all mutually independent)
  k_mega<<<NB_ROUTER + NB_CONVGU + NB_CONVD, 256, 0, stream>>>(
      x, rw, out_logits, out_topi, out_topw, tk_e, tk_w, cnts,
      wg, wu, wd, wgT, wuT, wdT);

  // scan + assign (single block, LDS cursors)
  k_scanassign<<<1, 256, 0, stream>>>(cnts, tk_e, tk_w, offs, tile_e, tile_rt,
                                      ntiles, perm, pw, inv);
  k_gather<<<NASSIGN, 256, 0, stream>>>(x, perm, xg);

  // fused gate+up -> gact   (44 ct x 72 ti = 3168 blocks, %8==0)
  k_gemm_gu256f<<<dim3((ID / 128) * MAXT256), 512, 0, stream>>>(
      xg, wgT, wuT, cnts, offs, tile_e, tile_rt, ntiles, gact);
  // down (*pw) -> dbuf bf16   (8 ct x 72 ti = 576 blocks)
  k_gemm_dn256<<<dim3((HD / 256) * MAXT256), 512, 0, stream>>>(
      gact, wdT, cnts, offs, tile_e, tile_rt, ntiles, pw, dbuf);
  // out[t] = dbuf[inv0] + dbuf[inv1]
  k_combine<<<NTOK, 256, 0, stream>>>(dbuf, inv, outp);
}